// Round 13
// baseline (647.830 us; speedup 1.0000x reference)
//
#include <hip/hip_runtime.h>
#include <cstdint>

// ---------------- CSR build ----------------

__global__ __launch_bounds__(256) void k_hist(const int* __restrict__ ei,
        int E, int E2, int* __restrict__ deg) {
    int e = blockIdx.x * 256 + threadIdx.x;
    if (e >= E2) return;
    int dst = (e < E) ? ei[E + e] : (e - E);
    atomicAdd(&deg[dst], 1);
}

// 3-phase multi-block exclusive scan of deg[0..N) -> row_start[0..N]
__global__ __launch_bounds__(256) void k_scanA(const int* __restrict__ deg,
        int* __restrict__ partials, int N) {
    int t = threadIdx.x;
    int base = blockIdx.x * 2048 + t * 8;
    int s = 0;
    #pragma unroll
    for (int j = 0; j < 8; ++j) { int i = base + j; if (i < N) s += deg[i]; }
    #pragma unroll
    for (int off = 32; off >= 1; off >>= 1) s += __shfl_xor(s, off, 64);
    __shared__ int ws[4];
    if ((t & 63) == 0) ws[t >> 6] = s;
    __syncthreads();
    if (t == 0) partials[blockIdx.x] = ws[0] + ws[1] + ws[2] + ws[3];
}

__global__ __launch_bounds__(64) void k_scanB(int* __restrict__ partials,
        int nb, int* __restrict__ row_start, int N) {
    int lane = threadIdx.x;
    int run = 0;
    for (int b0 = 0; b0 < nb; b0 += 64) {
        int v = (b0 + lane < nb) ? partials[b0 + lane] : 0;
        int s = v;
        #pragma unroll
        for (int d = 1; d < 64; d <<= 1) {
            int u = __shfl_up(s, d, 64);
            if (lane >= d) s += u;
        }
        if (b0 + lane < nb) partials[b0 + lane] = run + s - v;  // exclusive
        run += __shfl(s, 63, 64);
    }
    if (lane == 0) row_start[N] = run;
}

__global__ __launch_bounds__(256) void k_scanC(const int* __restrict__ deg,
        const int* __restrict__ partials, int* __restrict__ row_start, int N) {
    int t = threadIdx.x;
    int base = blockIdx.x * 2048 + t * 8;
    int v[8], s = 0;
    #pragma unroll
    for (int j = 0; j < 8; ++j) { int i = base + j; v[j] = (i < N) ? deg[i] : 0; s += v[j]; }
    int lane = t & 63, w = t >> 6;
    int incl = s;
    #pragma unroll
    for (int d = 1; d < 64; d <<= 1) {
        int u = __shfl_up(incl, d, 64);
        if (lane >= d) incl += u;
    }
    __shared__ int wsum[4];
    if (lane == 63) wsum[w] = incl;
    __syncthreads();
    int woff = 0;
    #pragma unroll
    for (int i = 0; i < 4; ++i) if (i < w) woff += wsum[i];
    int run = partials[blockIdx.x] + woff + incl - s;
    #pragma unroll
    for (int j = 0; j < 8; ++j) {
        int i = base + j;
        if (i < N) row_start[i] = run;
        run += v[j];
    }
}

__global__ __launch_bounds__(256) void k_scatter(const int* __restrict__ ei,
        int E, int E2, const int* __restrict__ row_start, int* __restrict__ cursor,
        int* __restrict__ csr_src) {
    int e = blockIdx.x * 256 + threadIdx.x;
    if (e >= E2) return;
    int src, dst;
    if (e < E) { src = ei[e]; dst = ei[E + e]; }
    else       { src = e - E; dst = src; }
    int pos = row_start[dst] + atomicAdd(&cursor[dst], 1);
    csr_src[pos] = src;
}

// ---------------- GEMM1: [N,512] @ [512,64] -> h1 [N,64] ----------------
// One wave per 64 rows. Lane (rg=l>>3, cg=l&7) computes an 8x8 register tile:
// rows rg*8..+7, cols cg*8..+7. W K-tile (BK=32, 8KB) in wave-private LDS
// (no barriers; same-wave DS ops are in-order), staged with register
// prefetch. x comes straight from global/L1 per-lane (float4 per 4-k chunk,
// software-pipelined). Per kk: 2 ds_read_b128 vs 64 FMAs -> VALU-bound.

__global__ __launch_bounds__(64) void k_gemm1(const float* __restrict__ x,
        const float* __restrict__ W, float* __restrict__ h1, int N) {
    __shared__ float ws[32][64];
    int l = threadIdx.x;
    int rg = l >> 3, cg = l & 7;
    int row0 = blockIdx.x * 64 + rg * 8;
    const float* xp[8];
    #pragma unroll
    for (int i = 0; i < 8; ++i)
        xp[i] = x + (size_t)min(row0 + i, N - 1) * 512;  // clamp; masked at store

    // W staging: 512 float4 per tile; lane handles fidx = l + 64u
    float4 wpre[8];
    #pragma unroll
    for (int u = 0; u < 8; ++u) {
        int fidx = l + 64 * u;
        wpre[u] = *(const float4*)(W + (size_t)(fidx >> 4) * 64 + (fidx & 15) * 4);
    }
    float4 xv[8];
    #pragma unroll
    for (int i = 0; i < 8; ++i) xv[i] = *(const float4*)(xp[i]);

    float acc[8][8] = {};
    for (int t = 0; t < 16; ++t) {
        int k0 = t * 32;
        #pragma unroll
        for (int u = 0; u < 8; ++u) {
            int fidx = l + 64 * u;
            *(float4*)&ws[fidx >> 4][(fidx & 15) * 4] = wpre[u];
        }
        if (t < 15) {
            #pragma unroll
            for (int u = 0; u < 8; ++u) {
                int fidx = l + 64 * u;
                wpre[u] = *(const float4*)(W + (size_t)(k0 + 32 + (fidx >> 4)) * 64
                                           + (fidx & 15) * 4);
            }
        }
        #pragma unroll
        for (int c4 = 0; c4 < 8; ++c4) {      // 4-k chunks within the tile
            float4 xn[8];
            int nk = k0 + c4 * 4 + 4;         // next chunk's k offset
            if (nk < 512) {
                #pragma unroll
                for (int i = 0; i < 8; ++i) xn[i] = *(const float4*)(xp[i] + nk);
            }
            #pragma unroll
            for (int m = 0; m < 4; ++m) {
                int kk = c4 * 4 + m;
                float4 wA = *(const float4*)&ws[kk][cg * 8];
                float4 wB = *(const float4*)&ws[kk][cg * 8 + 4];
                #pragma unroll
                for (int i = 0; i < 8; ++i) {
                    float a = (m == 0) ? xv[i].x : (m == 1) ? xv[i].y
                            : (m == 2) ? xv[i].z : xv[i].w;
                    acc[i][0] = fmaf(a, wA.x, acc[i][0]);
                    acc[i][1] = fmaf(a, wA.y, acc[i][1]);
                    acc[i][2] = fmaf(a, wA.z, acc[i][2]);
                    acc[i][3] = fmaf(a, wA.w, acc[i][3]);
                    acc[i][4] = fmaf(a, wB.x, acc[i][4]);
                    acc[i][5] = fmaf(a, wB.y, acc[i][5]);
                    acc[i][6] = fmaf(a, wB.z, acc[i][6]);
                    acc[i][7] = fmaf(a, wB.w, acc[i][7]);
                }
            }
            if (nk < 512) {
                #pragma unroll
                for (int i = 0; i < 8; ++i) xv[i] = xn[i];
            }
        }
    }
    #pragma unroll
    for (int i = 0; i < 8; ++i) {
        int row = row0 + i;
        if (row < N) {
            float* op = h1 + (size_t)row * 64 + cg * 8;
            *(float4*)op       = make_float4(acc[i][0], acc[i][1], acc[i][2], acc[i][3]);
            *(float4*)(op + 4) = make_float4(acc[i][4], acc[i][5], acc[i][6], acc[i][7]);
        }
    }
}

// ---------------- GEMM2: [N,64] @ [64,128] -> h2 [N,128] ----------------

__global__ __launch_bounds__(256) void k_gemm2(const float* __restrict__ hin,
        const float* __restrict__ W, float* __restrict__ h2, int N) {
    __shared__ float xs[64][65];
    __shared__ float ws[64][128];
    int t = threadIdx.x;
    int row0 = blockIdx.x * 64;
    #pragma unroll
    for (int u = 0; u < 4; ++u) {
        int idx = t + u * 256;
        int r = idx >> 4, f = idx & 15;
        int grow = row0 + r;
        float4 v = make_float4(0.f, 0.f, 0.f, 0.f);
        if (grow < N) v = *(const float4*)(hin + (size_t)grow * 64 + f * 4);
        xs[r][f * 4 + 0] = v.x; xs[r][f * 4 + 1] = v.y;
        xs[r][f * 4 + 2] = v.z; xs[r][f * 4 + 3] = v.w;
    }
    #pragma unroll
    for (int u = 0; u < 8; ++u) {
        int idx = t + u * 256;
        int kr = idx >> 5, c4 = (idx & 31) * 4;
        *(float4*)&ws[kr][c4] = *(const float4*)(W + (size_t)kr * 128 + c4);
    }
    __syncthreads();
    int c0 = (t & 15) * 8;
    int r0 = (t >> 4) * 4;
    float4 acc[4][2] = {};
    #pragma unroll 8
    for (int kk = 0; kk < 64; ++kk) {
        float4 w0 = *(const float4*)&ws[kk][c0];
        float4 w1 = *(const float4*)&ws[kk][c0 + 4];
        #pragma unroll
        for (int i = 0; i < 4; ++i) {
            float a = xs[r0 + i][kk];
            acc[i][0].x += a * w0.x; acc[i][0].y += a * w0.y;
            acc[i][0].z += a * w0.z; acc[i][0].w += a * w0.w;
            acc[i][1].x += a * w1.x; acc[i][1].y += a * w1.y;
            acc[i][1].z += a * w1.z; acc[i][1].w += a * w1.w;
        }
    }
    #pragma unroll
    for (int i = 0; i < 4; ++i) {
        int row = row0 + r0 + i;
        if (row < N) {
            *(float4*)(h2 + (size_t)row * 128 + c0) = acc[i][0];
            *(float4*)(h2 + (size_t)row * 128 + c0 + 4) = acc[i][1];
        }
    }
}

// ---------------- attention coefficients ----------------

__global__ __launch_bounds__(256) void k_att1(const float* __restrict__ h1,
        const float* __restrict__ att_src, const float* __restrict__ att_dst,
        float* __restrict__ a_s, float* __restrict__ a_d, int NH) {
    int i = blockIdx.x * 256 + threadIdx.x;
    if (i >= NH) return;
    int h = i & 7;
    const float* hp = h1 + (size_t)i * 8;
    const float* sp = att_src + h * 8;
    const float* dp = att_dst + h * 8;
    float s = 0.f, d = 0.f;
    #pragma unroll
    for (int c = 0; c < 8; ++c) { float v = hp[c]; s += v * sp[c]; d += v * dp[c]; }
    a_s[i] = s; a_d[i] = d;
}

__global__ __launch_bounds__(256) void k_att2(const float* __restrict__ h2,
        const float* __restrict__ att_src, const float* __restrict__ att_dst,
        float* __restrict__ a_s, float* __restrict__ a_d, int N) {
    int node = blockIdx.x * 4 + (threadIdx.x >> 6);
    int lane = threadIdx.x & 63;
    if (node >= N) return;
    const float* hp = h2 + (size_t)node * 128;
    float v0 = hp[lane], v1 = hp[lane + 64];
    float s = v0 * att_src[lane] + v1 * att_src[lane + 64];
    float d = v0 * att_dst[lane] + v1 * att_dst[lane + 64];
    #pragma unroll
    for (int off = 32; off >= 1; off >>= 1) {
        s += __shfl_xor(s, off, 64);
        d += __shfl_xor(d, off, 64);
    }
    if (lane == 0) { a_s[node] = s; a_d[node] = d; }
}

// ---------------- GAT layer 1 (H=8, C=8), single-pass + bias + ELU ----------------

__global__ __launch_bounds__(256) void k_gat1(
        const int* __restrict__ row_start, const int* __restrict__ csr_src,
        const float* __restrict__ h1,
        const float* __restrict__ a_src, const float* __restrict__ a_dst,
        const float* __restrict__ bias, float* __restrict__ outp, int N) {
    __shared__ float wlds[4][512];            // per-wave weight slab [j*8+h]
    int node = blockIdx.x * 4 + (threadIdx.x >> 6);
    int lane = threadIdx.x & 63;
    if (node >= N) return;
    float* mylds = wlds[threadIdx.x >> 6];
    int h = lane >> 3;
    int start = row_start[node], end = row_start[node + 1];

    float ad8[8];
    #pragma unroll
    for (int hh = 0; hh < 8; ++hh) ad8[hh] = a_dst[(size_t)node * 8 + hh];

    float dh[8] = {0.f,0.f,0.f,0.f,0.f,0.f,0.f,0.f};
    float acc = 0.f;
    for (int base = start; base < end; base += 64) {
        int idx = base + lane;
        int cnt = min(64, end - base);
        int sv = 0;
        if (idx < end) {
            sv = csr_src[idx];
            float4 s0 = *(const float4*)(a_src + (size_t)sv * 8);
            float4 s1 = *(const float4*)(a_src + (size_t)sv * 8 + 4);
            float al[8] = { s0.x + ad8[0], s0.y + ad8[1], s0.z + ad8[2], s0.w + ad8[3],
                            s1.x + ad8[4], s1.y + ad8[5], s1.z + ad8[6], s1.w + ad8[7] };
            float o[8];
            #pragma unroll
            for (int hh = 0; hh < 8; ++hh) {
                float a = al[hh];
                a = a > 0.f ? a : 0.2f * a;
                o[hh] = __expf(a);
                dh[hh] += o[hh];
            }
            *(float4*)&mylds[lane * 8]     = make_float4(o[0], o[1], o[2], o[3]);
            *(float4*)&mylds[lane * 8 + 4] = make_float4(o[4], o[5], o[6], o[7]);
        }
        // edge-serial weighted gather; weights from wave-private LDS
        if (cnt == 64) {
            #pragma unroll 4
            for (int j = 0; j < 64; ++j) {
                int s = __shfl(sv, j, 64);
                float w = mylds[j * 8 + h];
                acc += h1[(size_t)s * 64 + lane] * w;
            }
        } else {
            for (int j = 0; j < cnt; ++j) {
                int s = __shfl(sv, j, 64);
                float w = mylds[j * 8 + h];
                acc += h1[(size_t)s * 64 + lane] * w;
            }
        }
    }
    #pragma unroll
    for (int hh = 0; hh < 8; ++hh) {
        #pragma unroll
        for (int off = 32; off >= 1; off >>= 1) dh[hh] += __shfl_xor(dh[hh], off, 64);
    }
    float den = dh[0];
    #pragma unroll
    for (int hh = 1; hh < 8; ++hh) den = (h == hh) ? dh[hh] : den;
    float inv = 1.f / (den + 1e-16f);
    float v = acc * inv + bias[lane];
    outp[(size_t)node * 64 + lane] = v > 0.f ? v : __expf(v) - 1.f;  // ELU
}

// ---------------- GAT layer 2 (H=1, C=128), single-pass + bias ----------------

__global__ __launch_bounds__(256) void k_gat2(
        const int* __restrict__ row_start, const int* __restrict__ csr_src,
        const float* __restrict__ h2,
        const float* __restrict__ a_src, const float* __restrict__ a_dst,
        const float* __restrict__ bias, float* __restrict__ outp, int N) {
    int node = blockIdx.x * 4 + (threadIdx.x >> 6);
    int lane = threadIdx.x & 63;
    if (node >= N) return;
    int start = row_start[node], end = row_start[node + 1];
    float adst = a_dst[node];

    float dsum = 0.f;
    float acc0 = 0.f, acc1 = 0.f;
    for (int base = start; base < end; base += 64) {
        int idx = base + lane;
        int cnt = min(64, end - base);
        int sv = 0;
        float wv = 0.f;
        if (idx < end) {
            sv = csr_src[idx];
            float a = a_src[sv] + adst;
            a = a > 0.f ? a : 0.2f * a;
            wv = __expf(a);
            dsum += wv;
        }
        if (cnt == 64) {
            #pragma unroll 4
            for (int j = 0; j < 64; ++j) {
                int s = __shfl(sv, j, 64);
                float w = __shfl(wv, j, 64);
                const float* hp = h2 + (size_t)s * 128;
                acc0 += hp[lane] * w;
                acc1 += hp[lane + 64] * w;
            }
        } else {
            for (int j = 0; j < cnt; ++j) {
                int s = __shfl(sv, j, 64);
                float w = __shfl(wv, j, 64);
                const float* hp = h2 + (size_t)s * 128;
                acc0 += hp[lane] * w;
                acc1 += hp[lane + 64] * w;
            }
        }
    }
    #pragma unroll
    for (int off = 32; off >= 1; off >>= 1) dsum += __shfl_xor(dsum, off, 64);
    float inv = 1.f / (dsum + 1e-16f);
    outp[(size_t)node * 128 + lane]      = acc0 * inv + bias[lane];
    outp[(size_t)node * 128 + lane + 64] = acc1 * inv + bias[lane + 64];
}

// ---------------- launcher ----------------

extern "C" void kernel_launch(void* const* d_in, const int* in_sizes, int n_in,
                              void* d_out, int out_size, void* d_ws, size_t ws_size,
                              hipStream_t stream) {
    const float* x   = (const float*)d_in[0];
    const int*   ei  = (const int*)d_in[1];     // integer inputs arrive as int32
    const float* W1  = (const float*)d_in[2];
    const float* as1 = (const float*)d_in[3];
    const float* ad1 = (const float*)d_in[4];
    const float* b1  = (const float*)d_in[5];
    const float* W2  = (const float*)d_in[6];
    const float* as2 = (const float*)d_in[7];
    const float* ad2 = (const float*)d_in[8];
    const float* b2  = (const float*)d_in[9];
    int N  = in_sizes[0] / 512;
    int E  = in_sizes[1] / 2;
    int E2 = E + N;

    char* wsp = (char*)d_ws;
    size_t off = 0;
    auto alloc = [&](size_t bytes) {
        char* p = wsp + off;
        off = (off + bytes + 255) & ~(size_t)255;
        return p;
    };
    float* h1   = (float*)alloc((size_t)N * 64 * 4);
    float* hmid = (float*)alloc((size_t)N * 64 * 4);
    float* h2   = (float*)alloc((size_t)N * 128 * 4);
    float* a1s  = (float*)alloc((size_t)N * 8 * 4);
    float* a1d  = (float*)alloc((size_t)N * 8 * 4);
    float* a2s  = (float*)alloc((size_t)N * 4);
    float* a2d  = (float*)alloc((size_t)N * 4);
    int* deg    = (int*)alloc((size_t)2 * N * 4);  // deg | cursor
    int* cursor = deg + N;
    int* row_start = (int*)alloc((size_t)(N + 1) * 4);
    int* csr_src   = (int*)alloc((size_t)E2 * 4);
    int nbscan = (N + 2047) / 2048;
    int* partials  = (int*)alloc((size_t)nbscan * 4);
    (void)ws_size; (void)n_in; (void)out_size;

    hipMemsetAsync(deg, 0, (size_t)2 * N * 4, stream);
    int eb = (E2 + 255) / 256;
    k_hist<<<eb, 256, 0, stream>>>(ei, E, E2, deg);
    k_scanA<<<nbscan, 256, 0, stream>>>(deg, partials, N);
    k_scanB<<<1, 64, 0, stream>>>(partials, nbscan, row_start, N);
    k_scanC<<<nbscan, 256, 0, stream>>>(deg, partials, row_start, N);
    k_scatter<<<eb, 256, 0, stream>>>(ei, E, E2, row_start, cursor, csr_src);

    int gb64 = (N + 63) / 64;
    int nb4 = (N + 3) / 4;
    k_gemm1<<<gb64, 64, 0, stream>>>(x, W1, h1, N);
    k_att1<<<(N * 8 + 255) / 256, 256, 0, stream>>>(h1, as1, ad1, a1s, a1d, N * 8);
    k_gat1<<<nb4, 256, 0, stream>>>(row_start, csr_src, h1, a1s, a1d, b1, hmid, N);
    k_gemm2<<<gb64, 256, 0, stream>>>(hmid, W2, h2, N);
    k_att2<<<nb4, 256, 0, stream>>>(h2, as2, ad2, a2s, a2d, N);
    k_gat2<<<nb4, 256, 0, stream>>>(row_start, csr_src, h2, a2s, a2d, b2, (float*)d_out, N);
}

// Round 14
// 348.133 us; speedup vs baseline: 1.8609x; 1.8609x over previous
//
#include <hip/hip_runtime.h>
#include <cstdint>

// ---------------- CSR build ----------------

__global__ __launch_bounds__(256) void k_hist(const int* __restrict__ ei,
        int E, int E2, int* __restrict__ deg) {
    int e = blockIdx.x * 256 + threadIdx.x;
    if (e >= E2) return;
    int dst = (e < E) ? ei[E + e] : (e - E);
    atomicAdd(&deg[dst], 1);
}

// 3-phase multi-block exclusive scan of deg[0..N) -> row_start[0..N]
__global__ __launch_bounds__(256) void k_scanA(const int* __restrict__ deg,
        int* __restrict__ partials, int N) {
    int t = threadIdx.x;
    int base = blockIdx.x * 2048 + t * 8;
    int s = 0;
    #pragma unroll
    for (int j = 0; j < 8; ++j) { int i = base + j; if (i < N) s += deg[i]; }
    #pragma unroll
    for (int off = 32; off >= 1; off >>= 1) s += __shfl_xor(s, off, 64);
    __shared__ int ws[4];
    if ((t & 63) == 0) ws[t >> 6] = s;
    __syncthreads();
    if (t == 0) partials[blockIdx.x] = ws[0] + ws[1] + ws[2] + ws[3];
}

__global__ __launch_bounds__(64) void k_scanB(int* __restrict__ partials,
        int nb, int* __restrict__ row_start, int N) {
    int lane = threadIdx.x;
    int run = 0;
    for (int b0 = 0; b0 < nb; b0 += 64) {
        int v = (b0 + lane < nb) ? partials[b0 + lane] : 0;
        int s = v;
        #pragma unroll
        for (int d = 1; d < 64; d <<= 1) {
            int u = __shfl_up(s, d, 64);
            if (lane >= d) s += u;
        }
        if (b0 + lane < nb) partials[b0 + lane] = run + s - v;  // exclusive
        run += __shfl(s, 63, 64);
    }
    if (lane == 0) row_start[N] = run;
}

__global__ __launch_bounds__(256) void k_scanC(const int* __restrict__ deg,
        const int* __restrict__ partials, int* __restrict__ row_start, int N) {
    int t = threadIdx.x;
    int base = blockIdx.x * 2048 + t * 8;
    int v[8], s = 0;
    #pragma unroll
    for (int j = 0; j < 8; ++j) { int i = base + j; v[j] = (i < N) ? deg[i] : 0; s += v[j]; }
    int lane = t & 63, w = t >> 6;
    int incl = s;
    #pragma unroll
    for (int d = 1; d < 64; d <<= 1) {
        int u = __shfl_up(incl, d, 64);
        if (lane >= d) incl += u;
    }
    __shared__ int wsum[4];
    if (lane == 63) wsum[w] = incl;
    __syncthreads();
    int woff = 0;
    #pragma unroll
    for (int i = 0; i < 4; ++i) if (i < w) woff += wsum[i];
    int run = partials[blockIdx.x] + woff + incl - s;
    #pragma unroll
    for (int j = 0; j < 8; ++j) {
        int i = base + j;
        if (i < N) row_start[i] = run;
        run += v[j];
    }
}

__global__ __launch_bounds__(256) void k_scatter(const int* __restrict__ ei,
        int E, int E2, const int* __restrict__ row_start, int* __restrict__ cursor,
        int* __restrict__ csr_src) {
    int e = blockIdx.x * 256 + threadIdx.x;
    if (e >= E2) return;
    int src, dst;
    if (e < E) { src = ei[e]; dst = ei[E + e]; }
    else       { src = e - E; dst = src; }
    int pos = row_start[dst] + atomicAdd(&cursor[dst], 1);
    csr_src[pos] = src;
}

// ---------------- GEMM1: [N,512] @ [512,64] -> h1 [N,64] ----------------
// 64x64 tile, BK=16, 4x4 per-thread outputs. W staged in LDS (1 ds_read_b128
// per kk). x read DIRECTLY from global/L1: the 4 rows of a thread's tile are
// loaded as float4 chunks (16 lanes share each address -> coalesced
// broadcast), software-pipelined via xv/xn. Removes the x LDS tile, dropping
// per-kk LDS demand from ~28 clk to ~4 clk per wave -> VALU-bound.

__global__ __launch_bounds__(256) void k_gemm1(const float* __restrict__ x,
        const float* __restrict__ W, float* __restrict__ h1, int N) {
    __shared__ float ws[16][64];
    int t = threadIdx.x;
    int row0 = blockIdx.x * 64;
    int c0 = (t & 15) * 4;
    int r0 = (t >> 4) * 4;
    int wr = t >> 4, wc = (t & 15) * 4;    // W staging: thread writes 1 float4
    const float* xr[4];
    #pragma unroll
    for (int i = 0; i < 4; ++i)
        xr[i] = x + (size_t)min(row0 + r0 + i, N - 1) * 512;  // clamp; masked at store

    float4 wv = *(const float4*)(W + (size_t)wr * 64 + wc);
    float4 xv[4];
    #pragma unroll
    for (int i = 0; i < 4; ++i) xv[i] = *(const float4*)(xr[i]);

    float4 acc[4] = {};
    for (int k0 = 0; k0 < 512; k0 += 16) {
        __syncthreads();   // previous tile's readers done
        *(float4*)&ws[wr][wc] = wv;
        __syncthreads();
        if (k0 + 16 < 512)   // prefetch next W tile; latency hides under FMAs
            wv = *(const float4*)(W + (size_t)(k0 + 16 + wr) * 64 + wc);
        #pragma unroll
        for (int c4 = 0; c4 < 4; ++c4) {     // four 4-k chunks per tile
            float4 xn[4];
            int nk = k0 + c4 * 4 + 4;        // next chunk offset
            if (nk < 512) {
                #pragma unroll
                for (int i = 0; i < 4; ++i) xn[i] = *(const float4*)(xr[i] + nk);
            }
            #pragma unroll
            for (int m = 0; m < 4; ++m) {
                int kk = c4 * 4 + m;
                float4 w4 = *(const float4*)&ws[kk][c0];
                #pragma unroll
                for (int i = 0; i < 4; ++i) {
                    float a = (m == 0) ? xv[i].x : (m == 1) ? xv[i].y
                            : (m == 2) ? xv[i].z : xv[i].w;
                    acc[i].x = fmaf(a, w4.x, acc[i].x);
                    acc[i].y = fmaf(a, w4.y, acc[i].y);
                    acc[i].z = fmaf(a, w4.z, acc[i].z);
                    acc[i].w = fmaf(a, w4.w, acc[i].w);
                }
            }
            if (nk < 512) {
                #pragma unroll
                for (int i = 0; i < 4; ++i) xv[i] = xn[i];
            }
        }
    }
    #pragma unroll
    for (int i = 0; i < 4; ++i) {
        int row = row0 + r0 + i;
        if (row < N) *(float4*)(h1 + (size_t)row * 64 + c0) = acc[i];
    }
}

// ---------------- GEMM2: [N,64] @ [64,128] -> h2 [N,128] ----------------

__global__ __launch_bounds__(256) void k_gemm2(const float* __restrict__ hin,
        const float* __restrict__ W, float* __restrict__ h2, int N) {
    __shared__ float xs[64][65];
    __shared__ float ws[64][128];
    int t = threadIdx.x;
    int row0 = blockIdx.x * 64;
    #pragma unroll
    for (int u = 0; u < 4; ++u) {
        int idx = t + u * 256;
        int r = idx >> 4, f = idx & 15;
        int grow = row0 + r;
        float4 v = make_float4(0.f, 0.f, 0.f, 0.f);
        if (grow < N) v = *(const float4*)(hin + (size_t)grow * 64 + f * 4);
        xs[r][f * 4 + 0] = v.x; xs[r][f * 4 + 1] = v.y;
        xs[r][f * 4 + 2] = v.z; xs[r][f * 4 + 3] = v.w;
    }
    #pragma unroll
    for (int u = 0; u < 8; ++u) {
        int idx = t + u * 256;
        int kr = idx >> 5, c4 = (idx & 31) * 4;
        *(float4*)&ws[kr][c4] = *(const float4*)(W + (size_t)kr * 128 + c4);
    }
    __syncthreads();
    int c0 = (t & 15) * 8;
    int r0 = (t >> 4) * 4;
    float4 acc[4][2] = {};
    #pragma unroll 8
    for (int kk = 0; kk < 64; ++kk) {
        float4 w0 = *(const float4*)&ws[kk][c0];
        float4 w1 = *(const float4*)&ws[kk][c0 + 4];
        #pragma unroll
        for (int i = 0; i < 4; ++i) {
            float a = xs[r0 + i][kk];
            acc[i][0].x += a * w0.x; acc[i][0].y += a * w0.y;
            acc[i][0].z += a * w0.z; acc[i][0].w += a * w0.w;
            acc[i][1].x += a * w1.x; acc[i][1].y += a * w1.y;
            acc[i][1].z += a * w1.z; acc[i][1].w += a * w1.w;
        }
    }
    #pragma unroll
    for (int i = 0; i < 4; ++i) {
        int row = row0 + r0 + i;
        if (row < N) {
            *(float4*)(h2 + (size_t)row * 128 + c0) = acc[i][0];
            *(float4*)(h2 + (size_t)row * 128 + c0 + 4) = acc[i][1];
        }
    }
}

// ---------------- attention coefficients ----------------

__global__ __launch_bounds__(256) void k_att1(const float* __restrict__ h1,
        const float* __restrict__ att_src, const float* __restrict__ att_dst,
        float* __restrict__ a_s, float* __restrict__ a_d, int NH) {
    int i = blockIdx.x * 256 + threadIdx.x;
    if (i >= NH) return;
    int h = i & 7;
    const float* hp = h1 + (size_t)i * 8;
    const float* sp = att_src + h * 8;
    const float* dp = att_dst + h * 8;
    float s = 0.f, d = 0.f;
    #pragma unroll
    for (int c = 0; c < 8; ++c) { float v = hp[c]; s += v * sp[c]; d += v * dp[c]; }
    a_s[i] = s; a_d[i] = d;
}

__global__ __launch_bounds__(256) void k_att2(const float* __restrict__ h2,
        const float* __restrict__ att_src, const float* __restrict__ att_dst,
        float* __restrict__ a_s, float* __restrict__ a_d, int N) {
    int node = blockIdx.x * 4 + (threadIdx.x >> 6);
    int lane = threadIdx.x & 63;
    if (node >= N) return;
    const float* hp = h2 + (size_t)node * 128;
    float v0 = hp[lane], v1 = hp[lane + 64];
    float s = v0 * att_src[lane] + v1 * att_src[lane + 64];
    float d = v0 * att_dst[lane] + v1 * att_dst[lane + 64];
    #pragma unroll
    for (int off = 32; off >= 1; off >>= 1) {
        s += __shfl_xor(s, off, 64);
        d += __shfl_xor(d, off, 64);
    }
    if (lane == 0) { a_s[node] = s; a_d[node] = d; }
}

// ---------------- GAT layer 1 (H=8, C=8), single-pass + bias + ELU ----------------

__global__ __launch_bounds__(256) void k_gat1(
        const int* __restrict__ row_start, const int* __restrict__ csr_src,
        const float* __restrict__ h1,
        const float* __restrict__ a_src, const float* __restrict__ a_dst,
        const float* __restrict__ bias, float* __restrict__ outp, int N) {
    __shared__ float wlds[4][512];            // per-wave weight slab [j*8+h]
    int node = blockIdx.x * 4 + (threadIdx.x >> 6);
    int lane = threadIdx.x & 63;
    if (node >= N) return;
    float* mylds = wlds[threadIdx.x >> 6];
    int h = lane >> 3;
    int start = row_start[node], end = row_start[node + 1];

    float ad8[8];
    #pragma unroll
    for (int hh = 0; hh < 8; ++hh) ad8[hh] = a_dst[(size_t)node * 8 + hh];

    float dh[8] = {0.f,0.f,0.f,0.f,0.f,0.f,0.f,0.f};
    float acc = 0.f;
    for (int base = start; base < end; base += 64) {
        int idx = base + lane;
        int cnt = min(64, end - base);
        int sv = 0;
        if (idx < end) {
            sv = csr_src[idx];
            float4 s0 = *(const float4*)(a_src + (size_t)sv * 8);
            float4 s1 = *(const float4*)(a_src + (size_t)sv * 8 + 4);
            float al[8] = { s0.x + ad8[0], s0.y + ad8[1], s0.z + ad8[2], s0.w + ad8[3],
                            s1.x + ad8[4], s1.y + ad8[5], s1.z + ad8[6], s1.w + ad8[7] };
            float o[8];
            #pragma unroll
            for (int hh = 0; hh < 8; ++hh) {
                float a = al[hh];
                a = a > 0.f ? a : 0.2f * a;
                o[hh] = __expf(a);
                dh[hh] += o[hh];
            }
            *(float4*)&mylds[lane * 8]     = make_float4(o[0], o[1], o[2], o[3]);
            *(float4*)&mylds[lane * 8 + 4] = make_float4(o[4], o[5], o[6], o[7]);
        }
        // edge-serial weighted gather; weights from wave-private LDS
        if (cnt == 64) {
            #pragma unroll 4
            for (int j = 0; j < 64; ++j) {
                int s = __shfl(sv, j, 64);
                float w = mylds[j * 8 + h];
                acc += h1[(size_t)s * 64 + lane] * w;
            }
        } else {
            for (int j = 0; j < cnt; ++j) {
                int s = __shfl(sv, j, 64);
                float w = mylds[j * 8 + h];
                acc += h1[(size_t)s * 64 + lane] * w;
            }
        }
    }
    #pragma unroll
    for (int hh = 0; hh < 8; ++hh) {
        #pragma unroll
        for (int off = 32; off >= 1; off >>= 1) dh[hh] += __shfl_xor(dh[hh], off, 64);
    }
    float den = dh[0];
    #pragma unroll
    for (int hh = 1; hh < 8; ++hh) den = (h == hh) ? dh[hh] : den;
    float inv = 1.f / (den + 1e-16f);
    float v = acc * inv + bias[lane];
    outp[(size_t)node * 64 + lane] = v > 0.f ? v : __expf(v) - 1.f;  // ELU
}

// ---------------- GAT layer 2 (H=1, C=128), single-pass + bias ----------------

__global__ __launch_bounds__(256) void k_gat2(
        const int* __restrict__ row_start, const int* __restrict__ csr_src,
        const float* __restrict__ h2,
        const float* __restrict__ a_src, const float* __restrict__ a_dst,
        const float* __restrict__ bias, float* __restrict__ outp, int N) {
    int node = blockIdx.x * 4 + (threadIdx.x >> 6);
    int lane = threadIdx.x & 63;
    if (node >= N) return;
    int start = row_start[node], end = row_start[node + 1];
    float adst = a_dst[node];

    float dsum = 0.f;
    float acc0 = 0.f, acc1 = 0.f;
    for (int base = start; base < end; base += 64) {
        int idx = base + lane;
        int cnt = min(64, end - base);
        int sv = 0;
        float wv = 0.f;
        if (idx < end) {
            sv = csr_src[idx];
            float a = a_src[sv] + adst;
            a = a > 0.f ? a : 0.2f * a;
            wv = __expf(a);
            dsum += wv;
        }
        if (cnt == 64) {
            #pragma unroll 4
            for (int j = 0; j < 64; ++j) {
                int s = __shfl(sv, j, 64);
                float w = __shfl(wv, j, 64);
                const float* hp = h2 + (size_t)s * 128;
                acc0 += hp[lane] * w;
                acc1 += hp[lane + 64] * w;
            }
        } else {
            for (int j = 0; j < cnt; ++j) {
                int s = __shfl(sv, j, 64);
                float w = __shfl(wv, j, 64);
                const float* hp = h2 + (size_t)s * 128;
                acc0 += hp[lane] * w;
                acc1 += hp[lane + 64] * w;
            }
        }
    }
    #pragma unroll
    for (int off = 32; off >= 1; off >>= 1) dsum += __shfl_xor(dsum, off, 64);
    float inv = 1.f / (dsum + 1e-16f);
    outp[(size_t)node * 128 + lane]      = acc0 * inv + bias[lane];
    outp[(size_t)node * 128 + lane + 64] = acc1 * inv + bias[lane + 64];
}

// ---------------- launcher ----------------

extern "C" void kernel_launch(void* const* d_in, const int* in_sizes, int n_in,
                              void* d_out, int out_size, void* d_ws, size_t ws_size,
                              hipStream_t stream) {
    const float* x   = (const float*)d_in[0];
    const int*   ei  = (const int*)d_in[1];     // integer inputs arrive as int32
    const float* W1  = (const float*)d_in[2];
    const float* as1 = (const float*)d_in[3];
    const float* ad1 = (const float*)d_in[4];
    const float* b1  = (const float*)d_in[5];
    const float* W2  = (const float*)d_in[6];
    const float* as2 = (const float*)d_in[7];
    const float* ad2 = (const float*)d_in[8];
    const float* b2  = (const float*)d_in[9];
    int N  = in_sizes[0] / 512;
    int E  = in_sizes[1] / 2;
    int E2 = E + N;

    char* wsp = (char*)d_ws;
    size_t off = 0;
    auto alloc = [&](size_t bytes) {
        char* p = wsp + off;
        off = (off + bytes + 255) & ~(size_t)255;
        return p;
    };
    float* h1   = (float*)alloc((size_t)N * 64 * 4);
    float* hmid = (float*)alloc((size_t)N * 64 * 4);
    float* h2   = (float*)alloc((size_t)N * 128 * 4);
    float* a1s  = (float*)alloc((size_t)N * 8 * 4);
    float* a1d  = (float*)alloc((size_t)N * 8 * 4);
    float* a2s  = (float*)alloc((size_t)N * 4);
    float* a2d  = (float*)alloc((size_t)N * 4);
    int* deg    = (int*)alloc((size_t)2 * N * 4);  // deg | cursor
    int* cursor = deg + N;
    int* row_start = (int*)alloc((size_t)(N + 1) * 4);
    int* csr_src   = (int*)alloc((size_t)E2 * 4);
    int nbscan = (N + 2047) / 2048;
    int* partials  = (int*)alloc((size_t)nbscan * 4);
    (void)ws_size; (void)n_in; (void)out_size;

    hipMemsetAsync(deg, 0, (size_t)2 * N * 4, stream);
    int eb = (E2 + 255) / 256;
    k_hist<<<eb, 256, 0, stream>>>(ei, E, E2, deg);
    k_scanA<<<nbscan, 256, 0, stream>>>(deg, partials, N);
    k_scanB<<<1, 64, 0, stream>>>(partials, nbscan, row_start, N);
    k_scanC<<<nbscan, 256, 0, stream>>>(deg, partials, row_start, N);
    k_scatter<<<eb, 256, 0, stream>>>(ei, E, E2, row_start, cursor, csr_src);

    int gb64 = (N + 63) / 64;
    int nb4 = (N + 3) / 4;
    k_gemm1<<<gb64, 256, 0, stream>>>(x, W1, h1, N);
    k_att1<<<(N * 8 + 255) / 256, 256, 0, stream>>>(h1, as1, ad1, a1s, a1d, N * 8);
    k_gat1<<<nb4, 256, 0, stream>>>(row_start, csr_src, h1, a1s, a1d, b1, hmid, N);
    k_gemm2<<<gb64, 256, 0, stream>>>(hmid, W2, h2, N);
    k_att2<<<nb4, 256, 0, stream>>>(h2, as2, ad2, a2s, a2d, N);
    k_gat2<<<nb4, 256, 0, stream>>>(row_start, csr_src, h2, a2s, a2d, b2, (float*)d_out, N);
}

// Round 17
// 296.291 us; speedup vs baseline: 2.1865x; 1.1750x over previous
//
#include <hip/hip_runtime.h>
#include <cstdint>

typedef __attribute__((ext_vector_type(8))) __bf16 bf16x8;
typedef __attribute__((ext_vector_type(4))) float f32x4;

// ---------------- CSR build ----------------

__global__ __launch_bounds__(256) void k_hist(const int* __restrict__ ei,
        int E, int E2, int* __restrict__ deg) {
    int e = blockIdx.x * 256 + threadIdx.x;
    if (e >= E2) return;
    int dst = (e < E) ? ei[E + e] : (e - E);
    atomicAdd(&deg[dst], 1);
}

// 3-phase multi-block exclusive scan of deg[0..N) -> row_start[0..N]
__global__ __launch_bounds__(256) void k_scanA(const int* __restrict__ deg,
        int* __restrict__ partials, int N) {
    int t = threadIdx.x;
    int base = blockIdx.x * 2048 + t * 8;
    int s = 0;
    #pragma unroll
    for (int j = 0; j < 8; ++j) { int i = base + j; if (i < N) s += deg[i]; }
    #pragma unroll
    for (int off = 32; off >= 1; off >>= 1) s += __shfl_xor(s, off, 64);
    __shared__ int ws[4];
    if ((t & 63) == 0) ws[t >> 6] = s;
    __syncthreads();
    if (t == 0) partials[blockIdx.x] = ws[0] + ws[1] + ws[2] + ws[3];
}

__global__ __launch_bounds__(64) void k_scanB(int* __restrict__ partials,
        int nb, int* __restrict__ row_start, int N) {
    int lane = threadIdx.x;
    int run = 0;
    for (int b0 = 0; b0 < nb; b0 += 64) {
        int v = (b0 + lane < nb) ? partials[b0 + lane] : 0;
        int s = v;
        #pragma unroll
        for (int d = 1; d < 64; d <<= 1) {
            int u = __shfl_up(s, d, 64);
            if (lane >= d) s += u;
        }
        if (b0 + lane < nb) partials[b0 + lane] = run + s - v;  // exclusive
        run += __shfl(s, 63, 64);
    }
    if (lane == 0) row_start[N] = run;
}

__global__ __launch_bounds__(256) void k_scanC(const int* __restrict__ deg,
        const int* __restrict__ partials, int* __restrict__ row_start, int N) {
    int t = threadIdx.x;
    int base = blockIdx.x * 2048 + t * 8;
    int v[8], s = 0;
    #pragma unroll
    for (int j = 0; j < 8; ++j) { int i = base + j; v[j] = (i < N) ? deg[i] : 0; s += v[j]; }
    int lane = t & 63, w = t >> 6;
    int incl = s;
    #pragma unroll
    for (int d = 1; d < 64; d <<= 1) {
        int u = __shfl_up(incl, d, 64);
        if (lane >= d) incl += u;
    }
    __shared__ int wsum[4];
    if (lane == 63) wsum[w] = incl;
    __syncthreads();
    int woff = 0;
    #pragma unroll
    for (int i = 0; i < 4; ++i) if (i < w) woff += wsum[i];
    int run = partials[blockIdx.x] + woff + incl - s;
    #pragma unroll
    for (int j = 0; j < 8; ++j) {
        int i = base + j;
        if (i < N) row_start[i] = run;
        run += v[j];
    }
}

__global__ __launch_bounds__(256) void k_scatter(const int* __restrict__ ei,
        int E, int E2, const int* __restrict__ row_start, int* __restrict__ cursor,
        int* __restrict__ csr_src) {
    int e = blockIdx.x * 256 + threadIdx.x;
    if (e >= E2) return;
    int src, dst;
    if (e < E) { src = ei[e]; dst = ei[E + e]; }
    else       { src = e - E; dst = src; }
    int pos = row_start[dst] + atomicAdd(&cursor[dst], 1);
    csr_src[pos] = src;
}

// ---------------- GEMM1 (bf16 MFMA): [N,512] @ [512,64] -> h1 [N,64] -------
// Block = 4 waves = 64 rows x 64 cols. W1 is staged ONCE per block into LDS
// in fragment-linear order: frag (s,ct) for K-step s, col-tile ct; lane l's
// 16B B-fragment at BF[((s*4+ct)*64+l)*8]. B-frag load = 1 linear
// ds_read_b128 (conflict-free). A-frag read straight from fp32 x (2 float4
// + 8 cvt). mfma_f32_16x16x32_bf16: A row=l&15, k=(l>>4)*8+j; B col=l&15,
// same k; D col=l&15, row=(l>>4)*4+reg (m89-verified layout).

__global__ __launch_bounds__(256) void k_gemm1(const float* __restrict__ x,
        const float* __restrict__ W, float* __restrict__ h1, int N) {
    __shared__ __bf16 BF[32768];   // 16 K-steps x 4 col-tiles x 64 lanes x 8 bf16 = 64KB
    int t = threadIdx.x;

    // stage W (512x64 fp32 = 8192 float4) -> fragment-linear bf16 LDS
    #pragma unroll
    for (int u = 0; u < 32; ++u) {
        int f = t + 256 * u;                 // float4 index into W (8192 total)
        int k = f >> 4, n4 = (f & 15) * 4;
        float4 wv = *(const float4*)(W + (size_t)k * 64 + n4);
        int s = k >> 5, g = (k >> 3) & 3, j = k & 7;
        #pragma unroll
        for (int e = 0; e < 4; ++e) {
            int n = n4 + e;
            int ct = n >> 4;
            int lane = (n & 15) | (g << 4);
            float v = (e == 0) ? wv.x : (e == 1) ? wv.y : (e == 2) ? wv.z : wv.w;
            BF[(((s * 4 + ct) * 64 + lane) << 3) + j] = (__bf16)v;
        }
    }
    __syncthreads();

    int l = t & 63, w = t >> 6;
    int g = l >> 4;
    int arow = blockIdx.x * 64 + w * 16 + (l & 15);
    const float* xbase = x + (size_t)min(arow, N - 1) * 512 + g * 8;

    f32x4 acc[4] = {{0.f,0.f,0.f,0.f},{0.f,0.f,0.f,0.f},
                    {0.f,0.f,0.f,0.f},{0.f,0.f,0.f,0.f}};
    #pragma unroll 4
    for (int s = 0; s < 16; ++s) {
        float4 xa = *(const float4*)(xbase + s * 32);
        float4 xb = *(const float4*)(xbase + s * 32 + 4);
        bf16x8 a;
        a[0] = (__bf16)xa.x; a[1] = (__bf16)xa.y; a[2] = (__bf16)xa.z; a[3] = (__bf16)xa.w;
        a[4] = (__bf16)xb.x; a[5] = (__bf16)xb.y; a[6] = (__bf16)xb.z; a[7] = (__bf16)xb.w;
        #pragma unroll
        for (int ct = 0; ct < 4; ++ct) {
            bf16x8 b = *reinterpret_cast<const bf16x8*>(&BF[((s * 4 + ct) * 64 + l) << 3]);
            acc[ct] = __builtin_amdgcn_mfma_f32_16x16x32_bf16(a, b, acc[ct], 0, 0, 0);
        }
    }
    // D layout: col = l&15, row(inside 16x16) = g*4 + r
    int orow0 = blockIdx.x * 64 + w * 16 + g * 4;
    #pragma unroll
    for (int ct = 0; ct < 4; ++ct) {
        int col = ct * 16 + (l & 15);
        #pragma unroll
        for (int r = 0; r < 4; ++r) {
            int row = orow0 + r;
            if (row < N) h1[(size_t)row * 64 + col] = acc[ct][r];
        }
    }
}

// ---------------- GEMM2: [N,64] @ [64,128] -> h2 [N,128] ----------------

__global__ __launch_bounds__(256) void k_gemm2(const float* __restrict__ hin,
        const float* __restrict__ W, float* __restrict__ h2, int N) {
    __shared__ float xs[64][65];
    __shared__ float ws[64][128];
    int t = threadIdx.x;
    int row0 = blockIdx.x * 64;
    #pragma unroll
    for (int u = 0; u < 4; ++u) {
        int idx = t + u * 256;
        int r = idx >> 4, f = idx & 15;
        int grow = row0 + r;
        float4 v = make_float4(0.f, 0.f, 0.f, 0.f);
        if (grow < N) v = *(const float4*)(hin + (size_t)grow * 64 + f * 4);
        xs[r][f * 4 + 0] = v.x; xs[r][f * 4 + 1] = v.y;
        xs[r][f * 4 + 2] = v.z; xs[r][f * 4 + 3] = v.w;
    }
    #pragma unroll
    for (int u = 0; u < 8; ++u) {
        int idx = t + u * 256;
        int kr = idx >> 5, c4 = (idx & 31) * 4;
        *(float4*)&ws[kr][c4] = *(const float4*)(W + (size_t)kr * 128 + c4);
    }
    __syncthreads();
    int c0 = (t & 15) * 8;
    int r0 = (t >> 4) * 4;
    float4 acc[4][2] = {};
    #pragma unroll 8
    for (int kk = 0; kk < 64; ++kk) {
        float4 w0 = *(const float4*)&ws[kk][c0];
        float4 w1 = *(const float4*)&ws[kk][c0 + 4];
        #pragma unroll
        for (int i = 0; i < 4; ++i) {
            float a = xs[r0 + i][kk];
            acc[i][0].x += a * w0.x; acc[i][0].y += a * w0.y;
            acc[i][0].z += a * w0.z; acc[i][0].w += a * w0.w;
            acc[i][1].x += a * w1.x; acc[i][1].y += a * w1.y;
            acc[i][1].z += a * w1.z; acc[i][1].w += a * w1.w;
        }
    }
    #pragma unroll
    for (int i = 0; i < 4; ++i) {
        int row = row0 + r0 + i;
        if (row < N) {
            *(float4*)(h2 + (size_t)row * 128 + c0) = acc[i][0];
            *(float4*)(h2 + (size_t)row * 128 + c0 + 4) = acc[i][1];
        }
    }
}

// ---------------- attention coefficients ----------------

__global__ __launch_bounds__(256) void k_att1(const float* __restrict__ h1,
        const float* __restrict__ att_src, const float* __restrict__ att_dst,
        float* __restrict__ a_s, float* __restrict__ a_d, int NH) {
    int i = blockIdx.x * 256 + threadIdx.x;
    if (i >= NH) return;
    int h = i & 7;
    const float* hp = h1 + (size_t)i * 8;
    const float* sp = att_src + h * 8;
    const float* dp = att_dst + h * 8;
    float s = 0.f, d = 0.f;
    #pragma unroll
    for (int c = 0; c < 8; ++c) { float v = hp[c]; s += v * sp[c]; d += v * dp[c]; }
    a_s[i] = s; a_d[i] = d;
}

__global__ __launch_bounds__(256) void k_att2(const float* __restrict__ h2,
        const float* __restrict__ att_src, const float* __restrict__ att_dst,
        float* __restrict__ a_s, float* __restrict__ a_d, int N) {
    int node = blockIdx.x * 4 + (threadIdx.x >> 6);
    int lane = threadIdx.x & 63;
    if (node >= N) return;
    const float* hp = h2 + (size_t)node * 128;
    float v0 = hp[lane], v1 = hp[lane + 64];
    float s = v0 * att_src[lane] + v1 * att_src[lane + 64];
    float d = v0 * att_dst[lane] + v1 * att_dst[lane + 64];
    #pragma unroll
    for (int off = 32; off >= 1; off >>= 1) {
        s += __shfl_xor(s, off, 64);
        d += __shfl_xor(d, off, 64);
    }
    if (lane == 0) { a_s[node] = s; a_d[node] = d; }
}

// ---------------- GAT layer 1 (H=8, C=8), single-pass + bias + ELU ----------------

__global__ __launch_bounds__(256) void k_gat1(
        const int* __restrict__ row_start, const int* __restrict__ csr_src,
        const float* __restrict__ h1,
        const float* __restrict__ a_src, const float* __restrict__ a_dst,
        const float* __restrict__ bias, float* __restrict__ outp, int N) {
    __shared__ float wlds[4][512];            // per-wave weight slab [j*8+h]
    int node = blockIdx.x * 4 + (threadIdx.x >> 6);
    int lane = threadIdx.x & 63;
    if (node >= N) return;
    float* mylds = wlds[threadIdx.x >> 6];
    int h = lane >> 3;
    int start = row_start[node], end = row_start[node + 1];

    float ad8[8];
    #pragma unroll
    for (int hh = 0; hh < 8; ++hh) ad8[hh] = a_dst[(size_t)node * 8 + hh];

    float dh[8] = {0.f,0.f,0.f,0.f,0.f,0.f,0.f,0.f};
    float acc = 0.f;
    for (int base = start; base < end; base += 64) {
        int idx = base + lane;
        int cnt = min(64, end - base);
        int sv = 0;
        if (idx < end) {
            sv = csr_src[idx];
            float4 s0 = *(const float4*)(a_src + (size_t)sv * 8);
            float4 s1 = *(const float4*)(a_src + (size_t)sv * 8 + 4);
            float al[8] = { s0.x + ad8[0], s0.y + ad8[1], s0.z + ad8[2], s0.w + ad8[3],
                            s1.x + ad8[4], s1.y + ad8[5], s1.z + ad8[6], s1.w + ad8[7] };
            float o[8];
            #pragma unroll
            for (int hh = 0; hh < 8; ++hh) {
                float a = al[hh];
                a = a > 0.f ? a : 0.2f * a;
                o[hh] = __expf(a);
                dh[hh] += o[hh];
            }
            *(float4*)&mylds[lane * 8]     = make_float4(o[0], o[1], o[2], o[3]);
            *(float4*)&mylds[lane * 8 + 4] = make_float4(o[4], o[5], o[6], o[7]);
        }
        // edge-serial weighted gather; weights from wave-private LDS
        if (cnt == 64) {
            #pragma unroll 4
            for (int j = 0; j < 64; ++j) {
                int s = __shfl(sv, j, 64);
                float w = mylds[j * 8 + h];
                acc += h1[(size_t)s * 64 + lane] * w;
            }
        } else {
            for (int j = 0; j < cnt; ++j) {
                int s = __shfl(sv, j, 64);
                float w = mylds[j * 8 + h];
                acc += h1[(size_t)s * 64 + lane] * w;
            }
        }
    }
    #pragma unroll
    for (int hh = 0; hh < 8; ++hh) {
        #pragma unroll
        for (int off = 32; off >= 1; off >>= 1) dh[hh] += __shfl_xor(dh[hh], off, 64);
    }
    float den = dh[0];
    #pragma unroll
    for (int hh = 1; hh < 8; ++hh) den = (h == hh) ? dh[hh] : den;
    float inv = 1.f / (den + 1e-16f);
    float v = acc * inv + bias[lane];
    outp[(size_t)node * 64 + lane] = v > 0.f ? v : __expf(v) - 1.f;  // ELU
}

// ---------------- GAT layer 2 (H=1, C=128), single-pass + bias ----------------

__global__ __launch_bounds__(256) void k_gat2(
        const int* __restrict__ row_start, const int* __restrict__ csr_src,
        const float* __restrict__ h2,
        const float* __restrict__ a_src, const float* __restrict__ a_dst,
        const float* __restrict__ bias, float* __restrict__ outp, int N) {
    int node = blockIdx.x * 4 + (threadIdx.x >> 6);
    int lane = threadIdx.x & 63;
    if (node >= N) return;
    int start = row_start[node], end = row_start[node + 1];
    float adst = a_dst[node];

    float dsum = 0.f;
    float acc0 = 0.f, acc1 = 0.f;
    for (int base = start; base < end; base += 64) {
        int idx = base + lane;
        int cnt = min(64, end - base);
        int sv = 0;
        float wv = 0.f;
        if (idx < end) {
            sv = csr_src[idx];
            float a = a_src[sv] + adst;
            a = a > 0.f ? a : 0.2f * a;
            wv = __expf(a);
            dsum += wv;
        }
        if (cnt == 64) {
            #pragma unroll 4
            for (int j = 0; j < 64; ++j) {
                int s = __shfl(sv, j, 64);
                float w = __shfl(wv, j, 64);
                const float* hp = h2 + (size_t)s * 128;
                acc0 += hp[lane] * w;
                acc1 += hp[lane + 64] * w;
            }
        } else {
            for (int j = 0; j < cnt; ++j) {
                int s = __shfl(sv, j, 64);
                float w = __shfl(wv, j, 64);
                const float* hp = h2 + (size_t)s * 128;
                acc0 += hp[lane] * w;
                acc1 += hp[lane + 64] * w;
            }
        }
    }
    #pragma unroll
    for (int off = 32; off >= 1; off >>= 1) dsum += __shfl_xor(dsum, off, 64);
    float inv = 1.f / (dsum + 1e-16f);
    outp[(size_t)node * 128 + lane]      = acc0 * inv + bias[lane];
    outp[(size_t)node * 128 + lane + 64] = acc1 * inv + bias[lane + 64];
}

// ---------------- launcher ----------------

extern "C" void kernel_launch(void* const* d_in, const int* in_sizes, int n_in,
                              void* d_out, int out_size, void* d_ws, size_t ws_size,
                              hipStream_t stream) {
    const float* x   = (const float*)d_in[0];
    const int*   ei  = (const int*)d_in[1];     // integer inputs arrive as int32
    const float* W1  = (const float*)d_in[2];
    const float* as1 = (const float*)d_in[3];
    const float* ad1 = (const float*)d_in[4];
    const float* b1  = (const float*)d_in[5];
    const float* W2  = (const float*)d_in[6];
    const float* as2 = (const float*)d_in[7];
    const float* ad2 = (const float*)d_in[8];
    const float* b2  = (const float*)d_in[9];
    int N  = in_sizes[0] / 512;
    int E  = in_sizes[1] / 2;
    int E2 = E + N;

    char* wsp = (char*)d_ws;
    size_t off = 0;
    auto alloc = [&](size_t bytes) {
        char* p = wsp + off;
        off = (off + bytes + 255) & ~(size_t)255;
        return p;
    };
    float* h1   = (float*)alloc((size_t)N * 64 * 4);
    float* hmid = (float*)alloc((size_t)N * 64 * 4);
    float* h2   = (float*)alloc((size_t)N * 128 * 4);
    float* a1s  = (float*)alloc((size_t)N * 8 * 4);
    float* a1d  = (float*)alloc((size_t)N * 8 * 4);
    float* a2s  = (float*)alloc((size_t)N * 4);
    float* a2d  = (float*)alloc((size_t)N * 4);
    int* deg    = (int*)alloc((size_t)2 * N * 4);  // deg | cursor
    int* cursor = deg + N;
    int* row_start = (int*)alloc((size_t)(N + 1) * 4);
    int* csr_src   = (int*)alloc((size_t)E2 * 4);
    int nbscan = (N + 2047) / 2048;
    int* partials  = (int*)alloc((size_t)nbscan * 4);
    (void)ws_size; (void)n_in; (void)out_size;

    hipMemsetAsync(deg, 0, (size_t)2 * N * 4, stream);
    int eb = (E2 + 255) / 256;
    k_hist<<<eb, 256, 0, stream>>>(ei, E, E2, deg);
    k_scanA<<<nbscan, 256, 0, stream>>>(deg, partials, N);
    k_scanB<<<1, 64, 0, stream>>>(partials, nbscan, row_start, N);
    k_scanC<<<nbscan, 256, 0, stream>>>(deg, partials, row_start, N);
    k_scatter<<<eb, 256, 0, stream>>>(ei, E, E2, row_start, cursor, csr_src);

    int gb64 = (N + 63) / 64;
    int nb4 = (N + 3) / 4;
    k_gemm1<<<gb64, 256, 0, stream>>>(x, W1, h1, N);
    k_att1<<<(N * 8 + 255) / 256, 256, 0, stream>>>(h1, as1, ad1, a1s, a1d, N * 8);
    k_gat1<<<nb4, 256, 0, stream>>>(row_start, csr_src, h1, a1s, a1d, b1, hmid, N);
    k_gemm2<<<gb64, 256, 0, stream>>>(hmid, W2, h2, N);
    k_att2<<<nb4, 256, 0, stream>>>(h2, as2, ad2, a2s, a2d, N);
    k_gat2<<<nb4, 256, 0, stream>>>(row_start, csr_src, h2, a2s, a2d, b2, (float*)d_out, N);
}

// Round 18
// 258.239 us; speedup vs baseline: 2.5087x; 1.1474x over previous
//
#include <hip/hip_runtime.h>
#include <cstdint>

typedef __attribute__((ext_vector_type(8))) __bf16 bf16x8;
typedef __attribute__((ext_vector_type(4))) float f32x4;

// ---------------- CSR build ----------------

__global__ __launch_bounds__(256) void k_hist(const int* __restrict__ ei,
        int E, int E2, int* __restrict__ deg) {
    int e = blockIdx.x * 256 + threadIdx.x;
    if (e >= E2) return;
    int dst = (e < E) ? ei[E + e] : (e - E);
    atomicAdd(&deg[dst], 1);
}

// 3-phase multi-block exclusive scan of deg[0..N) -> row_start[0..N]
__global__ __launch_bounds__(256) void k_scanA(const int* __restrict__ deg,
        int* __restrict__ partials, int N) {
    int t = threadIdx.x;
    int base = blockIdx.x * 2048 + t * 8;
    int s = 0;
    #pragma unroll
    for (int j = 0; j < 8; ++j) { int i = base + j; if (i < N) s += deg[i]; }
    #pragma unroll
    for (int off = 32; off >= 1; off >>= 1) s += __shfl_xor(s, off, 64);
    __shared__ int ws[4];
    if ((t & 63) == 0) ws[t >> 6] = s;
    __syncthreads();
    if (t == 0) partials[blockIdx.x] = ws[0] + ws[1] + ws[2] + ws[3];
}

__global__ __launch_bounds__(64) void k_scanB(int* __restrict__ partials,
        int nb, int* __restrict__ row_start, int N) {
    int lane = threadIdx.x;
    int run = 0;
    for (int b0 = 0; b0 < nb; b0 += 64) {
        int v = (b0 + lane < nb) ? partials[b0 + lane] : 0;
        int s = v;
        #pragma unroll
        for (int d = 1; d < 64; d <<= 1) {
            int u = __shfl_up(s, d, 64);
            if (lane >= d) s += u;
        }
        if (b0 + lane < nb) partials[b0 + lane] = run + s - v;  // exclusive
        run += __shfl(s, 63, 64);
    }
    if (lane == 0) row_start[N] = run;
}

__global__ __launch_bounds__(256) void k_scanC(const int* __restrict__ deg,
        const int* __restrict__ partials, int* __restrict__ row_start, int N) {
    int t = threadIdx.x;
    int base = blockIdx.x * 2048 + t * 8;
    int v[8], s = 0;
    #pragma unroll
    for (int j = 0; j < 8; ++j) { int i = base + j; v[j] = (i < N) ? deg[i] : 0; s += v[j]; }
    int lane = t & 63, w = t >> 6;
    int incl = s;
    #pragma unroll
    for (int d = 1; d < 64; d <<= 1) {
        int u = __shfl_up(incl, d, 64);
        if (lane >= d) incl += u;
    }
    __shared__ int wsum[4];
    if (lane == 63) wsum[w] = incl;
    __syncthreads();
    int woff = 0;
    #pragma unroll
    for (int i = 0; i < 4; ++i) if (i < w) woff += wsum[i];
    int run = partials[blockIdx.x] + woff + incl - s;
    #pragma unroll
    for (int j = 0; j < 8; ++j) {
        int i = base + j;
        if (i < N) row_start[i] = run;
        run += v[j];
    }
}

__global__ __launch_bounds__(256) void k_scatter(const int* __restrict__ ei,
        int E, int E2, const int* __restrict__ row_start, int* __restrict__ cursor,
        int* __restrict__ csr_src) {
    int e = blockIdx.x * 256 + threadIdx.x;
    if (e >= E2) return;
    int src, dst;
    if (e < E) { src = ei[e]; dst = ei[E + e]; }
    else       { src = e - E; dst = src; }
    int pos = row_start[dst] + atomicAdd(&cursor[dst], 1);
    csr_src[pos] = src;
}

// ---------------- GEMM1 (bf16 MFMA): [N,512] @ [512,64] -> h1 [N,64] -------

__global__ __launch_bounds__(256) void k_gemm1(const float* __restrict__ x,
        const float* __restrict__ W, float* __restrict__ h1, int N) {
    __shared__ __bf16 BF[32768];   // 16 K-steps x 4 col-tiles x 64 lanes x 8 bf16 = 64KB
    int t = threadIdx.x;

    // stage W (512x64 fp32 = 8192 float4) -> fragment-linear bf16 LDS
    #pragma unroll
    for (int u = 0; u < 32; ++u) {
        int f = t + 256 * u;                 // float4 index into W (8192 total)
        int k = f >> 4, n4 = (f & 15) * 4;
        float4 wv = *(const float4*)(W + (size_t)k * 64 + n4);
        int s = k >> 5, g = (k >> 3) & 3, j = k & 7;
        #pragma unroll
        for (int e = 0; e < 4; ++e) {
            int n = n4 + e;
            int ct = n >> 4;
            int lane = (n & 15) | (g << 4);
            float v = (e == 0) ? wv.x : (e == 1) ? wv.y : (e == 2) ? wv.z : wv.w;
            BF[(((s * 4 + ct) * 64 + lane) << 3) + j] = (__bf16)v;
        }
    }
    __syncthreads();

    int l = t & 63, w = t >> 6;
    int g = l >> 4;
    int arow = blockIdx.x * 64 + w * 16 + (l & 15);
    const float* xbase = x + (size_t)min(arow, N - 1) * 512 + g * 8;

    f32x4 acc[4] = {{0.f,0.f,0.f,0.f},{0.f,0.f,0.f,0.f},
                    {0.f,0.f,0.f,0.f},{0.f,0.f,0.f,0.f}};
    #pragma unroll 4
    for (int s = 0; s < 16; ++s) {
        float4 xa = *(const float4*)(xbase + s * 32);
        float4 xb = *(const float4*)(xbase + s * 32 + 4);
        bf16x8 a;
        a[0] = (__bf16)xa.x; a[1] = (__bf16)xa.y; a[2] = (__bf16)xa.z; a[3] = (__bf16)xa.w;
        a[4] = (__bf16)xb.x; a[5] = (__bf16)xb.y; a[6] = (__bf16)xb.z; a[7] = (__bf16)xb.w;
        #pragma unroll
        for (int ct = 0; ct < 4; ++ct) {
            bf16x8 b = *reinterpret_cast<const bf16x8*>(&BF[((s * 4 + ct) * 64 + l) << 3]);
            acc[ct] = __builtin_amdgcn_mfma_f32_16x16x32_bf16(a, b, acc[ct], 0, 0, 0);
        }
    }
    // D layout: col = l&15, row(inside 16x16) = g*4 + r
    int orow0 = blockIdx.x * 64 + w * 16 + g * 4;
    #pragma unroll
    for (int ct = 0; ct < 4; ++ct) {
        int col = ct * 16 + (l & 15);
        #pragma unroll
        for (int r = 0; r < 4; ++r) {
            int row = orow0 + r;
            if (row < N) h1[(size_t)row * 64 + col] = acc[ct][r];
        }
    }
}

// ---------------- GEMM2: [N,64] @ [64,128] -> h2 [N,128] ----------------

__global__ __launch_bounds__(256) void k_gemm2(const float* __restrict__ hin,
        const float* __restrict__ W, float* __restrict__ h2, int N) {
    __shared__ float xs[64][65];
    __shared__ float ws[64][128];
    int t = threadIdx.x;
    int row0 = blockIdx.x * 64;
    #pragma unroll
    for (int u = 0; u < 4; ++u) {
        int idx = t + u * 256;
        int r = idx >> 4, f = idx & 15;
        int grow = row0 + r;
        float4 v = make_float4(0.f, 0.f, 0.f, 0.f);
        if (grow < N) v = *(const float4*)(hin + (size_t)grow * 64 + f * 4);
        xs[r][f * 4 + 0] = v.x; xs[r][f * 4 + 1] = v.y;
        xs[r][f * 4 + 2] = v.z; xs[r][f * 4 + 3] = v.w;
    }
    #pragma unroll
    for (int u = 0; u < 8; ++u) {
        int idx = t + u * 256;
        int kr = idx >> 5, c4 = (idx & 31) * 4;
        *(float4*)&ws[kr][c4] = *(const float4*)(W + (size_t)kr * 128 + c4);
    }
    __syncthreads();
    int c0 = (t & 15) * 8;
    int r0 = (t >> 4) * 4;
    float4 acc[4][2] = {};
    #pragma unroll 8
    for (int kk = 0; kk < 64; ++kk) {
        float4 w0 = *(const float4*)&ws[kk][c0];
        float4 w1 = *(const float4*)&ws[kk][c0 + 4];
        #pragma unroll
        for (int i = 0; i < 4; ++i) {
            float a = xs[r0 + i][kk];
            acc[i][0].x += a * w0.x; acc[i][0].y += a * w0.y;
            acc[i][0].z += a * w0.z; acc[i][0].w += a * w0.w;
            acc[i][1].x += a * w1.x; acc[i][1].y += a * w1.y;
            acc[i][1].z += a * w1.z; acc[i][1].w += a * w1.w;
        }
    }
    #pragma unroll
    for (int i = 0; i < 4; ++i) {
        int row = row0 + r0 + i;
        if (row < N) {
            *(float4*)(h2 + (size_t)row * 128 + c0) = acc[i][0];
            *(float4*)(h2 + (size_t)row * 128 + c0 + 4) = acc[i][1];
        }
    }
}

// ---------------- attention coefficients ----------------

__global__ __launch_bounds__(256) void k_att1(const float* __restrict__ h1,
        const float* __restrict__ att_src, const float* __restrict__ att_dst,
        float* __restrict__ a_s, float* __restrict__ a_d, int NH) {
    int i = blockIdx.x * 256 + threadIdx.x;
    if (i >= NH) return;
    int h = i & 7;
    const float* hp = h1 + (size_t)i * 8;
    const float* sp = att_src + h * 8;
    const float* dp = att_dst + h * 8;
    float s = 0.f, d = 0.f;
    #pragma unroll
    for (int c = 0; c < 8; ++c) { float v = hp[c]; s += v * sp[c]; d += v * dp[c]; }
    a_s[i] = s; a_d[i] = d;
}

__global__ __launch_bounds__(256) void k_att2(const float* __restrict__ h2,
        const float* __restrict__ att_src, const float* __restrict__ att_dst,
        float* __restrict__ a_s, float* __restrict__ a_d, int N) {
    int node = blockIdx.x * 4 + (threadIdx.x >> 6);
    int lane = threadIdx.x & 63;
    if (node >= N) return;
    const float* hp = h2 + (size_t)node * 128;
    float v0 = hp[lane], v1 = hp[lane + 64];
    float s = v0 * att_src[lane] + v1 * att_src[lane + 64];
    float d = v0 * att_dst[lane] + v1 * att_dst[lane + 64];
    #pragma unroll
    for (int off = 32; off >= 1; off >>= 1) {
        s += __shfl_xor(s, off, 64);
        d += __shfl_xor(d, off, 64);
    }
    if (lane == 0) { a_s[node] = s; a_d[node] = d; }
}

// ---------------- GAT layer 1 (H=8, C=8), multi-edge lanes + bias + ELU ------
// One wave per dst node. Lane = (j = lane>>3, c = lane&7): edge-slot j of 8,
// channel group c (= head c, channels c*8..c*8+7). Per iteration 8 edges:
// each lane computes its own weight (4B a_src gather + exp) and gathers 32B
// of h1[s] (2 float4), 8 FMAs into private acc[8]. j-reduction = 3 shfl_xor.

__global__ __launch_bounds__(256) void k_gat1(
        const int* __restrict__ row_start, const int* __restrict__ csr_src,
        const float* __restrict__ h1,
        const float* __restrict__ a_src, const float* __restrict__ a_dst,
        const float* __restrict__ bias, float* __restrict__ outp, int N) {
    int node = blockIdx.x * 4 + (threadIdx.x >> 6);
    int lane = threadIdx.x & 63;
    if (node >= N) return;
    int j = lane >> 3, c = lane & 7;
    int start = row_start[node], end = row_start[node + 1];
    float adc = a_dst[(size_t)node * 8 + c];

    float acc[8] = {};
    float wsum = 0.f;
    #pragma unroll 2
    for (int base = start; base < end; base += 8) {
        int idx = base + j;
        if (idx < end) {
            int s = csr_src[idx];
            float a = a_src[(size_t)s * 8 + c] + adc;
            a = a > 0.f ? a : 0.2f * a;
            float w = __expf(a);
            wsum += w;
            const float* hp = h1 + (size_t)s * 64 + c * 8;
            float4 v0 = *(const float4*)hp;
            float4 v1 = *(const float4*)(hp + 4);
            acc[0] = fmaf(w, v0.x, acc[0]); acc[1] = fmaf(w, v0.y, acc[1]);
            acc[2] = fmaf(w, v0.z, acc[2]); acc[3] = fmaf(w, v0.w, acc[3]);
            acc[4] = fmaf(w, v1.x, acc[4]); acc[5] = fmaf(w, v1.y, acc[5]);
            acc[6] = fmaf(w, v1.z, acc[6]); acc[7] = fmaf(w, v1.w, acc[7]);
        }
    }
    // reduce over edge-slots j (lane bits 3..5)
    #pragma unroll
    for (int off = 8; off <= 32; off <<= 1) {
        wsum += __shfl_xor(wsum, off, 64);
        #pragma unroll
        for (int e = 0; e < 8; ++e) acc[e] += __shfl_xor(acc[e], off, 64);
    }
    if (j == 0) {
        float inv = 1.f / (wsum + 1e-16f);
        float* op = outp + (size_t)node * 64 + c * 8;
        const float* bp = bias + c * 8;
        #pragma unroll
        for (int e = 0; e < 8; ++e) {
            float v = acc[e] * inv + bp[e];
            op[e] = v > 0.f ? v : __expf(v) - 1.f;  // ELU
        }
    }
}

// ---------------- GAT layer 2 (H=1, C=128), multi-edge lanes + bias ----------
// Lane = (j = lane>>4, c = lane&15): edge-slot j of 4, channels c*8..c*8+7.

__global__ __launch_bounds__(256) void k_gat2(
        const int* __restrict__ row_start, const int* __restrict__ csr_src,
        const float* __restrict__ h2,
        const float* __restrict__ a_src, const float* __restrict__ a_dst,
        const float* __restrict__ bias, float* __restrict__ outp, int N) {
    int node = blockIdx.x * 4 + (threadIdx.x >> 6);
    int lane = threadIdx.x & 63;
    if (node >= N) return;
    int j = lane >> 4, c = lane & 15;
    int start = row_start[node], end = row_start[node + 1];
    float adst = a_dst[node];

    float acc[8] = {};
    float wsum = 0.f;
    #pragma unroll 2
    for (int base = start; base < end; base += 4) {
        int idx = base + j;
        if (idx < end) {
            int s = csr_src[idx];
            float a = a_src[s] + adst;    // broadcast line per j-group
            a = a > 0.f ? a : 0.2f * a;
            float w = __expf(a);
            wsum += w;
            const float* hp = h2 + (size_t)s * 128 + c * 8;
            float4 v0 = *(const float4*)hp;
            float4 v1 = *(const float4*)(hp + 4);
            acc[0] = fmaf(w, v0.x, acc[0]); acc[1] = fmaf(w, v0.y, acc[1]);
            acc[2] = fmaf(w, v0.z, acc[2]); acc[3] = fmaf(w, v0.w, acc[3]);
            acc[4] = fmaf(w, v1.x, acc[4]); acc[5] = fmaf(w, v1.y, acc[5]);
            acc[6] = fmaf(w, v1.z, acc[6]); acc[7] = fmaf(w, v1.w, acc[7]);
        }
    }
    // reduce over edge-slots j (lane bits 4..5)
    #pragma unroll
    for (int off = 16; off <= 32; off <<= 1) {
        wsum += __shfl_xor(wsum, off, 64);
        #pragma unroll
        for (int e = 0; e < 8; ++e) acc[e] += __shfl_xor(acc[e], off, 64);
    }
    if (j == 0) {
        float inv = 1.f / (wsum + 1e-16f);
        float* op = outp + (size_t)node * 128 + c * 8;
        const float* bp = bias + c * 8;
        #pragma unroll
        for (int e = 0; e < 8; ++e)
            op[e] = acc[e] * inv + bp[e];
    }
}

// ---------------- launcher ----------------

extern "C" void kernel_launch(void* const* d_in, const int* in_sizes, int n_in,
                              void* d_out, int out_size, void* d_ws, size_t ws_size,
                              hipStream_t stream) {
    const float* x   = (const float*)d_in[0];
    const int*   ei  = (const int*)d_in[1];     // integer inputs arrive as int32
    const float* W1  = (const float*)d_in[2];
    const float* as1 = (const float*)d_in[3];
    const float* ad1 = (const float*)d_in[4];
    const float* b1  = (const float*)d_in[5];
    const float* W2  = (const float*)d_in[6];
    const float* as2 = (const float*)d_in[7];
    const float* ad2 = (const float*)d_in[8];
    const float* b2  = (const float*)d_in[9];
    int N  = in_sizes[0] / 512;
    int E  = in_sizes[1] / 2;
    int E2 = E + N;

    char* wsp = (char*)d_ws;
    size_t off = 0;
    auto alloc = [&](size_t bytes) {
        char* p = wsp + off;
        off = (off + bytes + 255) & ~(size_t)255;
        return p;
    };
    float* h1   = (float*)alloc((size_t)N * 64 * 4);
    float* hmid = (float*)alloc((size_t)N * 64 * 4);
    float* h2   = (float*)alloc((size_t)N * 128 * 4);
    float* a1s  = (float*)alloc((size_t)N * 8 * 4);
    float* a1d  = (float*)alloc((size_t)N * 8 * 4);
    float* a2s  = (float*)alloc((size_t)N * 4);
    float* a2d  = (float*)alloc((size_t)N * 4);
    int* deg    = (int*)alloc((size_t)2 * N * 4);  // deg | cursor
    int* cursor = deg + N;
    int* row_start = (int*)alloc((size_t)(N + 1) * 4);
    int* csr_src   = (int*)alloc((size_t)E2 * 4);
    int nbscan = (N + 2047) / 2048;
    int* partials  = (int*)alloc((size_t)nbscan * 4);
    (void)ws_size; (void)n_in; (void)out_size;

    hipMemsetAsync(deg, 0, (size_t)2 * N * 4, stream);
    int eb = (E2 + 255) / 256;
    k_hist<<<eb, 256, 0, stream>>>(ei, E, E2, deg);
    k_scanA<<<nbscan, 256, 0, stream>>>(deg, partials, N);
    k_scanB<<<1, 64, 0, stream>>>(partials, nbscan, row_start, N);
    k_scanC<<<nbscan, 256, 0, stream>>>(deg, partials, row_start, N);
    k_scatter<<<eb, 256, 0, stream>>>(ei, E, E2, row_start, cursor, csr_src);

    int gb64 = (N + 63) / 64;
    int nb4 = (N + 3) / 4;
    k_gemm1<<<gb64, 256, 0, stream>>>(x, W1, h1, N);
    k_att1<<<(N * 8 + 255) / 256, 256, 0, stream>>>(h1, as1, ad1, a1s, a1d, N * 8);
    k_gat1<<<nb4, 256, 0, stream>>>(row_start, csr_src, h1, a1s, a1d, b1, hmid, N);
    k_gemm2<<<gb64, 256, 0, stream>>>(hmid, W2, h2, N);
    k_att2<<<nb4, 256, 0, stream>>>(h2, as2, ad2, a2s, a2d, N);
    k_gat2<<<nb4, 256, 0, stream>>>(row_start, csr_src, h2, a2s, a2d, b2, (float*)d_out, N);
}

// Round 19
// 227.921 us; speedup vs baseline: 2.8423x; 1.1330x over previous
//
#include <hip/hip_runtime.h>
#include <cstdint>

typedef __attribute__((ext_vector_type(8))) __bf16 bf16x8;
typedef __attribute__((ext_vector_type(4))) float f32x4;

// ---------------- CSR build ----------------

__global__ __launch_bounds__(256) void k_hist(const int* __restrict__ ei,
        int E, int E2, int* __restrict__ deg) {
    int e = blockIdx.x * 256 + threadIdx.x;
    if (e >= E2) return;
    int dst = (e < E) ? ei[E + e] : (e - E);
    atomicAdd(&deg[dst], 1);
}

// 3-phase multi-block exclusive scan of deg[0..N) -> row_start[0..N]
__global__ __launch_bounds__(256) void k_scanA(const int* __restrict__ deg,
        int* __restrict__ partials, int N) {
    int t = threadIdx.x;
    int base = blockIdx.x * 2048 + t * 8;
    int s = 0;
    #pragma unroll
    for (int j = 0; j < 8; ++j) { int i = base + j; if (i < N) s += deg[i]; }
    #pragma unroll
    for (int off = 32; off >= 1; off >>= 1) s += __shfl_xor(s, off, 64);
    __shared__ int ws[4];
    if ((t & 63) == 0) ws[t >> 6] = s;
    __syncthreads();
    if (t == 0) partials[blockIdx.x] = ws[0] + ws[1] + ws[2] + ws[3];
}

__global__ __launch_bounds__(64) void k_scanB(int* __restrict__ partials,
        int nb, int* __restrict__ row_start, int N) {
    int lane = threadIdx.x;
    int run = 0;
    for (int b0 = 0; b0 < nb; b0 += 64) {
        int v = (b0 + lane < nb) ? partials[b0 + lane] : 0;
        int s = v;
        #pragma unroll
        for (int d = 1; d < 64; d <<= 1) {
            int u = __shfl_up(s, d, 64);
            if (lane >= d) s += u;
        }
        if (b0 + lane < nb) partials[b0 + lane] = run + s - v;  // exclusive
        run += __shfl(s, 63, 64);
    }
    if (lane == 0) row_start[N] = run;
}

__global__ __launch_bounds__(256) void k_scanC(const int* __restrict__ deg,
        const int* __restrict__ partials, int* __restrict__ row_start, int N) {
    int t = threadIdx.x;
    int base = blockIdx.x * 2048 + t * 8;
    int v[8], s = 0;
    #pragma unroll
    for (int j = 0; j < 8; ++j) { int i = base + j; v[j] = (i < N) ? deg[i] : 0; s += v[j]; }
    int lane = t & 63, w = t >> 6;
    int incl = s;
    #pragma unroll
    for (int d = 1; d < 64; d <<= 1) {
        int u = __shfl_up(incl, d, 64);
        if (lane >= d) incl += u;
    }
    __shared__ int wsum[4];
    if (lane == 63) wsum[w] = incl;
    __syncthreads();
    int woff = 0;
    #pragma unroll
    for (int i = 0; i < 4; ++i) if (i < w) woff += wsum[i];
    int run = partials[blockIdx.x] + woff + incl - s;
    #pragma unroll
    for (int j = 0; j < 8; ++j) {
        int i = base + j;
        if (i < N) row_start[i] = run;
        run += v[j];
    }
}

__global__ __launch_bounds__(256) void k_scatter(const int* __restrict__ ei,
        int E, int E2, const int* __restrict__ row_start, int* __restrict__ cursor,
        int* __restrict__ csr_src) {
    int e = blockIdx.x * 256 + threadIdx.x;
    if (e >= E2) return;
    int src, dst;
    if (e < E) { src = ei[e]; dst = ei[E + e]; }
    else       { src = e - E; dst = src; }
    int pos = row_start[dst] + atomicAdd(&cursor[dst], 1);
    csr_src[pos] = src;
}

// ---------------- GEMM1 (bf16 MFMA): [N,512] @ [512,64] -> h1, h1b ---------

__global__ __launch_bounds__(256) void k_gemm1(const float* __restrict__ x,
        const float* __restrict__ W, float* __restrict__ h1,
        __bf16* __restrict__ h1b, int N) {
    __shared__ __bf16 BF[32768];   // 16 K-steps x 4 col-tiles x 64 lanes x 8 bf16 = 64KB
    int t = threadIdx.x;

    // stage W (512x64 fp32 = 8192 float4) -> fragment-linear bf16 LDS
    #pragma unroll
    for (int u = 0; u < 32; ++u) {
        int f = t + 256 * u;                 // float4 index into W (8192 total)
        int k = f >> 4, n4 = (f & 15) * 4;
        float4 wv = *(const float4*)(W + (size_t)k * 64 + n4);
        int s = k >> 5, g = (k >> 3) & 3, j = k & 7;
        #pragma unroll
        for (int e = 0; e < 4; ++e) {
            int n = n4 + e;
            int ct = n >> 4;
            int lane = (n & 15) | (g << 4);
            float v = (e == 0) ? wv.x : (e == 1) ? wv.y : (e == 2) ? wv.z : wv.w;
            BF[(((s * 4 + ct) * 64 + lane) << 3) + j] = (__bf16)v;
        }
    }
    __syncthreads();

    int l = t & 63, w = t >> 6;
    int g = l >> 4;
    int arow = blockIdx.x * 64 + w * 16 + (l & 15);
    const float* xbase = x + (size_t)min(arow, N - 1) * 512 + g * 8;

    f32x4 acc[4] = {{0.f,0.f,0.f,0.f},{0.f,0.f,0.f,0.f},
                    {0.f,0.f,0.f,0.f},{0.f,0.f,0.f,0.f}};
    #pragma unroll 4
    for (int s = 0; s < 16; ++s) {
        float4 xa = *(const float4*)(xbase + s * 32);
        float4 xb = *(const float4*)(xbase + s * 32 + 4);
        bf16x8 a;
        a[0] = (__bf16)xa.x; a[1] = (__bf16)xa.y; a[2] = (__bf16)xa.z; a[3] = (__bf16)xa.w;
        a[4] = (__bf16)xb.x; a[5] = (__bf16)xb.y; a[6] = (__bf16)xb.z; a[7] = (__bf16)xb.w;
        #pragma unroll
        for (int ct = 0; ct < 4; ++ct) {
            bf16x8 b = *reinterpret_cast<const bf16x8*>(&BF[((s * 4 + ct) * 64 + l) << 3]);
            acc[ct] = __builtin_amdgcn_mfma_f32_16x16x32_bf16(a, b, acc[ct], 0, 0, 0);
        }
    }
    // D layout: col = l&15, row(inside 16x16) = g*4 + r
    int orow0 = blockIdx.x * 64 + w * 16 + g * 4;
    #pragma unroll
    for (int ct = 0; ct < 4; ++ct) {
        int col = ct * 16 + (l & 15);
        #pragma unroll
        for (int r = 0; r < 4; ++r) {
            int row = orow0 + r;
            if (row < N) {
                float v = acc[ct][r];
                h1[(size_t)row * 64 + col] = v;
                h1b[(size_t)row * 64 + col] = (__bf16)v;
            }
        }
    }
}

// ---------------- GEMM2: [N,64] @ [64,128] -> h2, h2b ----------------

__global__ __launch_bounds__(256) void k_gemm2(const float* __restrict__ hin,
        const float* __restrict__ W, float* __restrict__ h2,
        __bf16* __restrict__ h2b, int N) {
    __shared__ float xs[64][65];
    __shared__ float ws[64][128];
    int t = threadIdx.x;
    int row0 = blockIdx.x * 64;
    #pragma unroll
    for (int u = 0; u < 4; ++u) {
        int idx = t + u * 256;
        int r = idx >> 4, f = idx & 15;
        int grow = row0 + r;
        float4 v = make_float4(0.f, 0.f, 0.f, 0.f);
        if (grow < N) v = *(const float4*)(hin + (size_t)grow * 64 + f * 4);
        xs[r][f * 4 + 0] = v.x; xs[r][f * 4 + 1] = v.y;
        xs[r][f * 4 + 2] = v.z; xs[r][f * 4 + 3] = v.w;
    }
    #pragma unroll
    for (int u = 0; u < 8; ++u) {
        int idx = t + u * 256;
        int kr = idx >> 5, c4 = (idx & 31) * 4;
        *(float4*)&ws[kr][c4] = *(const float4*)(W + (size_t)kr * 128 + c4);
    }
    __syncthreads();
    int c0 = (t & 15) * 8;
    int r0 = (t >> 4) * 4;
    float4 acc[4][2] = {};
    #pragma unroll 8
    for (int kk = 0; kk < 64; ++kk) {
        float4 w0 = *(const float4*)&ws[kk][c0];
        float4 w1 = *(const float4*)&ws[kk][c0 + 4];
        #pragma unroll
        for (int i = 0; i < 4; ++i) {
            float a = xs[r0 + i][kk];
            acc[i][0].x += a * w0.x; acc[i][0].y += a * w0.y;
            acc[i][0].z += a * w0.z; acc[i][0].w += a * w0.w;
            acc[i][1].x += a * w1.x; acc[i][1].y += a * w1.y;
            acc[i][1].z += a * w1.z; acc[i][1].w += a * w1.w;
        }
    }
    #pragma unroll
    for (int i = 0; i < 4; ++i) {
        int row = row0 + r0 + i;
        if (row < N) {
            *(float4*)(h2 + (size_t)row * 128 + c0) = acc[i][0];
            *(float4*)(h2 + (size_t)row * 128 + c0 + 4) = acc[i][1];
            bf16x8 hb;
            hb[0] = (__bf16)acc[i][0].x; hb[1] = (__bf16)acc[i][0].y;
            hb[2] = (__bf16)acc[i][0].z; hb[3] = (__bf16)acc[i][0].w;
            hb[4] = (__bf16)acc[i][1].x; hb[5] = (__bf16)acc[i][1].y;
            hb[6] = (__bf16)acc[i][1].z; hb[7] = (__bf16)acc[i][1].w;
            *(bf16x8*)(h2b + (size_t)row * 128 + c0) = hb;
        }
    }
}

// ---------------- attention coefficients ----------------

__global__ __launch_bounds__(256) void k_att1(const float* __restrict__ h1,
        const float* __restrict__ att_src, const float* __restrict__ att_dst,
        float* __restrict__ a_s, float* __restrict__ a_d, int NH) {
    int i = blockIdx.x * 256 + threadIdx.x;
    if (i >= NH) return;
    int h = i & 7;
    const float* hp = h1 + (size_t)i * 8;
    const float* sp = att_src + h * 8;
    const float* dp = att_dst + h * 8;
    float s = 0.f, d = 0.f;
    #pragma unroll
    for (int c = 0; c < 8; ++c) { float v = hp[c]; s += v * sp[c]; d += v * dp[c]; }
    a_s[i] = s; a_d[i] = d;
}

__global__ __launch_bounds__(256) void k_att2(const float* __restrict__ h2,
        const float* __restrict__ att_src, const float* __restrict__ att_dst,
        float* __restrict__ a_s, float* __restrict__ a_d, int N) {
    int node = blockIdx.x * 4 + (threadIdx.x >> 6);
    int lane = threadIdx.x & 63;
    if (node >= N) return;
    const float* hp = h2 + (size_t)node * 128;
    float v0 = hp[lane], v1 = hp[lane + 64];
    float s = v0 * att_src[lane] + v1 * att_src[lane + 64];
    float d = v0 * att_dst[lane] + v1 * att_dst[lane + 64];
    #pragma unroll
    for (int off = 32; off >= 1; off >>= 1) {
        s += __shfl_xor(s, off, 64);
        d += __shfl_xor(d, off, 64);
    }
    if (lane == 0) { a_s[node] = s; a_d[node] = d; }
}

// ---------------- GAT layer 1 (H=8, C=8), multi-edge lanes + bias + ELU ------
// One wave per dst node. Lane = (j = lane>>3, c = lane&7): edge-slot j of 8,
// head c. Gather payload is bf16 (h1b) to halve per-XCD L2 fill traffic.

__global__ __launch_bounds__(256) void k_gat1(
        const int* __restrict__ row_start, const int* __restrict__ csr_src,
        const __bf16* __restrict__ h1b,
        const float* __restrict__ a_src, const float* __restrict__ a_dst,
        const float* __restrict__ bias, float* __restrict__ outp, int N) {
    int node = blockIdx.x * 4 + (threadIdx.x >> 6);
    int lane = threadIdx.x & 63;
    if (node >= N) return;
    int j = lane >> 3, c = lane & 7;
    int start = row_start[node], end = row_start[node + 1];
    float adc = a_dst[(size_t)node * 8 + c];

    float acc[8] = {};
    float wsum = 0.f;
    #pragma unroll 2
    for (int base = start; base < end; base += 8) {
        int idx = base + j;
        if (idx < end) {
            int s = csr_src[idx];
            float a = a_src[(size_t)s * 8 + c] + adc;
            a = a > 0.f ? a : 0.2f * a;
            float w = __expf(a);
            wsum += w;
            bf16x8 v = *(const bf16x8*)(h1b + (size_t)s * 64 + c * 8);
            #pragma unroll
            for (int e = 0; e < 8; ++e) acc[e] = fmaf(w, (float)v[e], acc[e]);
        }
    }
    // reduce over edge-slots j (lane bits 3..5)
    #pragma unroll
    for (int off = 8; off <= 32; off <<= 1) {
        wsum += __shfl_xor(wsum, off, 64);
        #pragma unroll
        for (int e = 0; e < 8; ++e) acc[e] += __shfl_xor(acc[e], off, 64);
    }
    if (j == 0) {
        float inv = 1.f / (wsum + 1e-16f);
        float* op = outp + (size_t)node * 64 + c * 8;
        const float* bp = bias + c * 8;
        #pragma unroll
        for (int e = 0; e < 8; ++e) {
            float v = acc[e] * inv + bp[e];
            op[e] = v > 0.f ? v : __expf(v) - 1.f;  // ELU
        }
    }
}

// ---------------- GAT layer 2 (H=1, C=128), multi-edge lanes + bias ----------
// Lane = (j = lane>>4, c = lane&15). Gather payload bf16 (h2b).

__global__ __launch_bounds__(256) void k_gat2(
        const int* __restrict__ row_start, const int* __restrict__ csr_src,
        const __bf16* __restrict__ h2b,
        const float* __restrict__ a_src, const float* __restrict__ a_dst,
        const float* __restrict__ bias, float* __restrict__ outp, int N) {
    int node = blockIdx.x * 4 + (threadIdx.x >> 6);
    int lane = threadIdx.x & 63;
    if (node >= N) return;
    int j = lane >> 4, c = lane & 15;
    int start = row_start[node], end = row_start[node + 1];
    float adst = a_dst[node];

    float acc[8] = {};
    float wsum = 0.f;
    #pragma unroll 2
    for (int base = start; base < end; base += 4) {
        int idx = base + j;
        if (idx < end) {
            int s = csr_src[idx];
            float a = a_src[s] + adst;    // broadcast line per j-group
            a = a > 0.f ? a : 0.2f * a;
            float w = __expf(a);
            wsum += w;
            bf16x8 v = *(const bf16x8*)(h2b + (size_t)s * 128 + c * 8);
            #pragma unroll
            for (int e = 0; e < 8; ++e) acc[e] = fmaf(w, (float)v[e], acc[e]);
        }
    }
    // reduce over edge-slots j (lane bits 4..5)
    #pragma unroll
    for (int off = 16; off <= 32; off <<= 1) {
        wsum += __shfl_xor(wsum, off, 64);
        #pragma unroll
        for (int e = 0; e < 8; ++e) acc[e] += __shfl_xor(acc[e], off, 64);
    }
    if (j == 0) {
        float inv = 1.f / (wsum + 1e-16f);
        float* op = outp + (size_t)node * 128 + c * 8;
        const float* bp = bias + c * 8;
        #pragma unroll
        for (int e = 0; e < 8; ++e)
            op[e] = acc[e] * inv + bp[e];
    }
}

// ---------------- launcher ----------------

extern "C" void kernel_launch(void* const* d_in, const int* in_sizes, int n_in,
                              void* d_out, int out_size, void* d_ws, size_t ws_size,
                              hipStream_t stream) {
    const float* x   = (const float*)d_in[0];
    const int*   ei  = (const int*)d_in[1];     // integer inputs arrive as int32
    const float* W1  = (const float*)d_in[2];
    const float* as1 = (const float*)d_in[3];
    const float* ad1 = (const float*)d_in[4];
    const float* b1  = (const float*)d_in[5];
    const float* W2  = (const float*)d_in[6];
    const float* as2 = (const float*)d_in[7];
    const float* ad2 = (const float*)d_in[8];
    const float* b2  = (const float*)d_in[9];
    int N  = in_sizes[0] / 512;
    int E  = in_sizes[1] / 2;
    int E2 = E + N;

    char* wsp = (char*)d_ws;
    size_t off = 0;
    auto alloc = [&](size_t bytes) {
        char* p = wsp + off;
        off = (off + bytes + 255) & ~(size_t)255;
        return p;
    };
    float*  h1   = (float*)alloc((size_t)N * 64 * 4);
    __bf16* h1b  = (__bf16*)alloc((size_t)N * 64 * 2);
    float*  hmid = (float*)alloc((size_t)N * 64 * 4);
    float*  h2   = (float*)alloc((size_t)N * 128 * 4);
    __bf16* h2b  = (__bf16*)alloc((size_t)N * 128 * 2);
    float*  a1s  = (float*)alloc((size_t)N * 8 * 4);
    float*  a1d  = (float*)alloc((size_t)N * 8 * 4);
    float*  a2s  = (float*)alloc((size_t)N * 4);
    float*  a2d  = (float*)alloc((size_t)N * 4);
    int* deg    = (int*)alloc((size_t)2 * N * 4);  // deg | cursor
    int* cursor = deg + N;
    int* row_start = (int*)alloc((size_t)(N + 1) * 4);
    int* csr_src   = (int*)alloc((size_t)E2 * 4);
    int nbscan = (N + 2047) / 2048;
    int* partials  = (int*)alloc((size_t)nbscan * 4);
    (void)ws_size; (void)n_in; (void)out_size;

    hipMemsetAsync(deg, 0, (size_t)2 * N * 4, stream);
    int eb = (E2 + 255) / 256;
    k_hist<<<eb, 256, 0, stream>>>(ei, E, E2, deg);
    k_scanA<<<nbscan, 256, 0, stream>>>(deg, partials, N);
    k_scanB<<<1, 64, 0, stream>>>(partials, nbscan, row_start, N);
    k_scanC<<<nbscan, 256, 0, stream>>>(deg, partials, row_start, N);
    k_scatter<<<eb, 256, 0, stream>>>(ei, E, E2, row_start, cursor, csr_src);

    int gb64 = (N + 63) / 64;
    int nb4 = (N + 3) / 4;
    k_gemm1<<<gb64, 256, 0, stream>>>(x, W1, h1, h1b, N);
    k_att1<<<(N * 8 + 255) / 256, 256, 0, stream>>>(h1, as1, ad1, a1s, a1d, N * 8);
    k_gat1<<<nb4, 256, 0, stream>>>(row_start, csr_src, h1b, a1s, a1d, b1, hmid, N);
    k_gemm2<<<gb64, 256, 0, stream>>>(hmid, W2, h2, h2b, N);
    k_att2<<<nb4, 256, 0, stream>>>(h2, as2, ad2, a2s, a2d, N);
    k_gat2<<<nb4, 256, 0, stream>>>(row_start, csr_src, h2b, a2s, a2d, b2, (float*)d_out, N);
}

// Round 20
// 225.440 us; speedup vs baseline: 2.8736x; 1.0110x over previous
//
#include <hip/hip_runtime.h>
#include <cstdint>

typedef __attribute__((ext_vector_type(8))) __bf16 bf16x8;
typedef __attribute__((ext_vector_type(4))) float f32x4;

// ---------------- CSR build ----------------

__global__ __launch_bounds__(256) void k_hist(const int* __restrict__ ei,
        int E, int E2, int* __restrict__ deg) {
    int e = blockIdx.x * 256 + threadIdx.x;
    if (e >= E2) return;
    int dst = (e < E) ? ei[E + e] : (e - E);
    atomicAdd(&deg[dst], 1);
}

// 3-phase multi-block exclusive scan of deg[0..N) -> row_start[0..N]
__global__ __launch_bounds__(256) void k_scanA(const int* __restrict__ deg,
        int* __restrict__ partials, int N) {
    int t = threadIdx.x;
    int base = blockIdx.x * 2048 + t * 8;
    int s = 0;
    #pragma unroll
    for (int j = 0; j < 8; ++j) { int i = base + j; if (i < N) s += deg[i]; }
    #pragma unroll
    for (int off = 32; off >= 1; off >>= 1) s += __shfl_xor(s, off, 64);
    __shared__ int ws[4];
    if ((t & 63) == 0) ws[t >> 6] = s;
    __syncthreads();
    if (t == 0) partials[blockIdx.x] = ws[0] + ws[1] + ws[2] + ws[3];
}

__global__ __launch_bounds__(64) void k_scanB(int* __restrict__ partials,
        int nb, int* __restrict__ row_start, int N) {
    int lane = threadIdx.x;
    int run = 0;
    for (int b0 = 0; b0 < nb; b0 += 64) {
        int v = (b0 + lane < nb) ? partials[b0 + lane] : 0;
        int s = v;
        #pragma unroll
        for (int d = 1; d < 64; d <<= 1) {
            int u = __shfl_up(s, d, 64);
            if (lane >= d) s += u;
        }
        if (b0 + lane < nb) partials[b0 + lane] = run + s - v;  // exclusive
        run += __shfl(s, 63, 64);
    }
    if (lane == 0) row_start[N] = run;
}

__global__ __launch_bounds__(256) void k_scanC(const int* __restrict__ deg,
        const int* __restrict__ partials, int* __restrict__ row_start, int N) {
    int t = threadIdx.x;
    int base = blockIdx.x * 2048 + t * 8;
    int v[8], s = 0;
    #pragma unroll
    for (int j = 0; j < 8; ++j) { int i = base + j; v[j] = (i < N) ? deg[i] : 0; s += v[j]; }
    int lane = t & 63, w = t >> 6;
    int incl = s;
    #pragma unroll
    for (int d = 1; d < 64; d <<= 1) {
        int u = __shfl_up(incl, d, 64);
        if (lane >= d) incl += u;
    }
    __shared__ int wsum[4];
    if (lane == 63) wsum[w] = incl;
    __syncthreads();
    int woff = 0;
    #pragma unroll
    for (int i = 0; i < 4; ++i) if (i < w) woff += wsum[i];
    int run = partials[blockIdx.x] + woff + incl - s;
    #pragma unroll
    for (int j = 0; j < 8; ++j) {
        int i = base + j;
        if (i < N) row_start[i] = run;
        run += v[j];
    }
}

__global__ __launch_bounds__(256) void k_scatter(const int* __restrict__ ei,
        int E, int E2, const int* __restrict__ row_start, int* __restrict__ cursor,
        int* __restrict__ csr_src) {
    int e = blockIdx.x * 256 + threadIdx.x;
    if (e >= E2) return;
    int src, dst;
    if (e < E) { src = ei[e]; dst = ei[E + e]; }
    else       { src = e - E; dst = src; }
    int pos = row_start[dst] + atomicAdd(&cursor[dst], 1);
    csr_src[pos] = src;
}

// ---------------- W1 -> fragment-linear bf16 (once) ----------------
// Wb1[((s*4+ct)*64 + lane)*8 + j] = bf16(W[k*64+n]),
// where k = s*32 + g*8 + j, n = ct*16 + (lane&15), g = lane>>4.

__global__ __launch_bounds__(256) void k_wconv(const float* __restrict__ W,
        __bf16* __restrict__ Wb) {
    int e = blockIdx.x * 256 + threadIdx.x;   // 32768 elements
    int k = e >> 6, n = e & 63;
    int s = k >> 5, g = (k >> 3) & 3, j = k & 7;
    int ct = n >> 4;
    int lane = (n & 15) | (g << 4);
    Wb[(((s * 4 + ct) * 64 + lane) << 3) + j] = (__bf16)W[e];
}

// ---------------- GEMM1 (bf16 MFMA, LDS-free): [N,512]@[512,64] -> h1, h1b --
// Block = 4 waves = 64 rows. B-fragments load directly from the 64KB
// fragment-linear Wb1 (per-lane coalesced 16B, L2-resident). A-frags from
// fp32 x (2 float4 + cvt). No LDS, no barriers.

__global__ __launch_bounds__(256) void k_gemm1(const float* __restrict__ x,
        const __bf16* __restrict__ Wb, float* __restrict__ h1,
        __bf16* __restrict__ h1b, int N) {
    int t = threadIdx.x;
    int l = t & 63, w = t >> 6;
    int g = l >> 4;
    int arow = blockIdx.x * 64 + w * 16 + (l & 15);
    const float* xbase = x + (size_t)min(arow, N - 1) * 512 + g * 8;

    f32x4 acc[4] = {{0.f,0.f,0.f,0.f},{0.f,0.f,0.f,0.f},
                    {0.f,0.f,0.f,0.f},{0.f,0.f,0.f,0.f}};
    #pragma unroll 4
    for (int s = 0; s < 16; ++s) {
        float4 xa = *(const float4*)(xbase + s * 32);
        float4 xb = *(const float4*)(xbase + s * 32 + 4);
        bf16x8 a;
        a[0] = (__bf16)xa.x; a[1] = (__bf16)xa.y; a[2] = (__bf16)xa.z; a[3] = (__bf16)xa.w;
        a[4] = (__bf16)xb.x; a[5] = (__bf16)xb.y; a[6] = (__bf16)xb.z; a[7] = (__bf16)xb.w;
        #pragma unroll
        for (int ct = 0; ct < 4; ++ct) {
            bf16x8 b = *reinterpret_cast<const bf16x8*>(Wb + (((s * 4 + ct) * 64 + l) << 3));
            acc[ct] = __builtin_amdgcn_mfma_f32_16x16x32_bf16(a, b, acc[ct], 0, 0, 0);
        }
    }
    // D layout: col = l&15, row(inside 16x16) = g*4 + r
    int orow0 = blockIdx.x * 64 + w * 16 + g * 4;
    #pragma unroll
    for (int ct = 0; ct < 4; ++ct) {
        int col = ct * 16 + (l & 15);
        #pragma unroll
        for (int r = 0; r < 4; ++r) {
            int row = orow0 + r;
            if (row < N) {
                float v = acc[ct][r];
                h1[(size_t)row * 64 + col] = v;
                h1b[(size_t)row * 64 + col] = (__bf16)v;
            }
        }
    }
}

// ---------------- GEMM2: [N,64] @ [64,128] -> h2, h2b ----------------

__global__ __launch_bounds__(256) void k_gemm2(const float* __restrict__ hin,
        const float* __restrict__ W, float* __restrict__ h2,
        __bf16* __restrict__ h2b, int N) {
    __shared__ float xs[64][65];
    __shared__ float ws[64][128];
    int t = threadIdx.x;
    int row0 = blockIdx.x * 64;
    #pragma unroll
    for (int u = 0; u < 4; ++u) {
        int idx = t + u * 256;
        int r = idx >> 4, f = idx & 15;
        int grow = row0 + r;
        float4 v = make_float4(0.f, 0.f, 0.f, 0.f);
        if (grow < N) v = *(const float4*)(hin + (size_t)grow * 64 + f * 4);
        xs[r][f * 4 + 0] = v.x; xs[r][f * 4 + 1] = v.y;
        xs[r][f * 4 + 2] = v.z; xs[r][f * 4 + 3] = v.w;
    }
    #pragma unroll
    for (int u = 0; u < 8; ++u) {
        int idx = t + u * 256;
        int kr = idx >> 5, c4 = (idx & 31) * 4;
        *(float4*)&ws[kr][c4] = *(const float4*)(W + (size_t)kr * 128 + c4);
    }
    __syncthreads();
    int c0 = (t & 15) * 8;
    int r0 = (t >> 4) * 4;
    float4 acc[4][2] = {};
    #pragma unroll 8
    for (int kk = 0; kk < 64; ++kk) {
        float4 w0 = *(const float4*)&ws[kk][c0];
        float4 w1 = *(const float4*)&ws[kk][c0 + 4];
        #pragma unroll
        for (int i = 0; i < 4; ++i) {
            float a = xs[r0 + i][kk];
            acc[i][0].x += a * w0.x; acc[i][0].y += a * w0.y;
            acc[i][0].z += a * w0.z; acc[i][0].w += a * w0.w;
            acc[i][1].x += a * w1.x; acc[i][1].y += a * w1.y;
            acc[i][1].z += a * w1.z; acc[i][1].w += a * w1.w;
        }
    }
    #pragma unroll
    for (int i = 0; i < 4; ++i) {
        int row = row0 + r0 + i;
        if (row < N) {
            *(float4*)(h2 + (size_t)row * 128 + c0) = acc[i][0];
            *(float4*)(h2 + (size_t)row * 128 + c0 + 4) = acc[i][1];
            bf16x8 hb;
            hb[0] = (__bf16)acc[i][0].x; hb[1] = (__bf16)acc[i][0].y;
            hb[2] = (__bf16)acc[i][0].z; hb[3] = (__bf16)acc[i][0].w;
            hb[4] = (__bf16)acc[i][1].x; hb[5] = (__bf16)acc[i][1].y;
            hb[6] = (__bf16)acc[i][1].z; hb[7] = (__bf16)acc[i][1].w;
            *(bf16x8*)(h2b + (size_t)row * 128 + c0) = hb;
        }
    }
}

// ---------------- attention coefficients ----------------

__global__ __launch_bounds__(256) void k_att1(const float* __restrict__ h1,
        const float* __restrict__ att_src, const float* __restrict__ att_dst,
        float* __restrict__ a_s, float* __restrict__ a_d, int NH) {
    int i = blockIdx.x * 256 + threadIdx.x;
    if (i >= NH) return;
    int h = i & 7;
    const float* hp = h1 + (size_t)i * 8;
    const float* sp = att_src + h * 8;
    const float* dp = att_dst + h * 8;
    float s = 0.f, d = 0.f;
    #pragma unroll
    for (int c = 0; c < 8; ++c) { float v = hp[c]; s += v * sp[c]; d += v * dp[c]; }
    a_s[i] = s; a_d[i] = d;
}

__global__ __launch_bounds__(256) void k_att2(const float* __restrict__ h2,
        const float* __restrict__ att_src, const float* __restrict__ att_dst,
        float* __restrict__ a_s, float* __restrict__ a_d, int N) {
    int node = blockIdx.x * 4 + (threadIdx.x >> 6);
    int lane = threadIdx.x & 63;
    if (node >= N) return;
    const float* hp = h2 + (size_t)node * 128;
    float v0 = hp[lane], v1 = hp[lane + 64];
    float s = v0 * att_src[lane] + v1 * att_src[lane + 64];
    float d = v0 * att_dst[lane] + v1 * att_dst[lane + 64];
    #pragma unroll
    for (int off = 32; off >= 1; off >>= 1) {
        s += __shfl_xor(s, off, 64);
        d += __shfl_xor(d, off, 64);
    }
    if (lane == 0) { a_s[node] = s; a_d[node] = d; }
}

// ---------------- GAT layer 1 (H=8, C=8), multi-edge lanes + bias + ELU ------

__global__ __launch_bounds__(256) void k_gat1(
        const int* __restrict__ row_start, const int* __restrict__ csr_src,
        const __bf16* __restrict__ h1b,
        const float* __restrict__ a_src, const float* __restrict__ a_dst,
        const float* __restrict__ bias, float* __restrict__ outp, int N) {
    int node = blockIdx.x * 4 + (threadIdx.x >> 6);
    int lane = threadIdx.x & 63;
    if (node >= N) return;
    int j = lane >> 3, c = lane & 7;
    int start = row_start[node], end = row_start[node + 1];
    float adc = a_dst[(size_t)node * 8 + c];

    float acc[8] = {};
    float wsum = 0.f;
    #pragma unroll 2
    for (int base = start; base < end; base += 8) {
        int idx = base + j;
        if (idx < end) {
            int s = csr_src[idx];
            float a = a_src[(size_t)s * 8 + c] + adc;
            a = a > 0.f ? a : 0.2f * a;
            float w = __expf(a);
            wsum += w;
            bf16x8 v = *(const bf16x8*)(h1b + (size_t)s * 64 + c * 8);
            #pragma unroll
            for (int e = 0; e < 8; ++e) acc[e] = fmaf(w, (float)v[e], acc[e]);
        }
    }
    // reduce over edge-slots j (lane bits 3..5)
    #pragma unroll
    for (int off = 8; off <= 32; off <<= 1) {
        wsum += __shfl_xor(wsum, off, 64);
        #pragma unroll
        for (int e = 0; e < 8; ++e) acc[e] += __shfl_xor(acc[e], off, 64);
    }
    if (j == 0) {
        float inv = 1.f / (wsum + 1e-16f);
        float* op = outp + (size_t)node * 64 + c * 8;
        const float* bp = bias + c * 8;
        #pragma unroll
        for (int e = 0; e < 8; ++e) {
            float v = acc[e] * inv + bp[e];
            op[e] = v > 0.f ? v : __expf(v) - 1.f;  // ELU
        }
    }
}

// ---------------- GAT layer 2 (H=1, C=128), multi-edge lanes + bias ----------

__global__ __launch_bounds__(256) void k_gat2(
        const int* __restrict__ row_start, const int* __restrict__ csr_src,
        const __bf16* __restrict__ h2b,
        const float* __restrict__ a_src, const float* __restrict__ a_dst,
        const float* __restrict__ bias, float* __restrict__ outp, int N) {
    int node = blockIdx.x * 4 + (threadIdx.x >> 6);
    int lane = threadIdx.x & 63;
    if (node >= N) return;
    int j = lane >> 4, c = lane & 15;
    int start = row_start[node], end = row_start[node + 1];
    float adst = a_dst[node];

    float acc[8] = {};
    float wsum = 0.f;
    #pragma unroll 2
    for (int base = start; base < end; base += 4) {
        int idx = base + j;
        if (idx < end) {
            int s = csr_src[idx];
            float a = a_src[s] + adst;    // broadcast line per j-group
            a = a > 0.f ? a : 0.2f * a;
            float w = __expf(a);
            wsum += w;
            bf16x8 v = *(const bf16x8*)(h2b + (size_t)s * 128 + c * 8);
            #pragma unroll
            for (int e = 0; e < 8; ++e) acc[e] = fmaf(w, (float)v[e], acc[e]);
        }
    }
    // reduce over edge-slots j (lane bits 4..5)
    #pragma unroll
    for (int off = 16; off <= 32; off <<= 1) {
        wsum += __shfl_xor(wsum, off, 64);
        #pragma unroll
        for (int e = 0; e < 8; ++e) acc[e] += __shfl_xor(acc[e], off, 64);
    }
    if (j == 0) {
        float inv = 1.f / (wsum + 1e-16f);
        float* op = outp + (size_t)node * 128 + c * 8;
        const float* bp = bias + c * 8;
        #pragma unroll
        for (int e = 0; e < 8; ++e)
            op[e] = acc[e] * inv + bp[e];
    }
}

// ---------------- launcher ----------------

extern "C" void kernel_launch(void* const* d_in, const int* in_sizes, int n_in,
                              void* d_out, int out_size, void* d_ws, size_t ws_size,
                              hipStream_t stream) {
    const float* x   = (const float*)d_in[0];
    const int*   ei  = (const int*)d_in[1];     // integer inputs arrive as int32
    const float* W1  = (const float*)d_in[2];
    const float* as1 = (const float*)d_in[3];
    const float* ad1 = (const float*)d_in[4];
    const float* b1  = (const float*)d_in[5];
    const float* W2  = (const float*)d_in[6];
    const float* as2 = (const float*)d_in[7];
    const float* ad2 = (const float*)d_in[8];
    const float* b2  = (const float*)d_in[9];
    int N  = in_sizes[0] / 512;
    int E  = in_sizes[1] / 2;
    int E2 = E + N;

    char* wsp = (char*)d_ws;
    size_t off = 0;
    auto alloc = [&](size_t bytes) {
        char* p = wsp + off;
        off = (off + bytes + 255) & ~(size_t)255;
        return p;
    };
    float*  h1   = (float*)alloc((size_t)N * 64 * 4);
    __bf16* h1b  = (__bf16*)alloc((size_t)N * 64 * 2);
    float*  hmid = (float*)alloc((size_t)N * 64 * 4);
    float*  h2   = (float*)alloc((size_t)N * 128 * 4);
    __bf16* h2b  = (__bf16*)alloc((size_t)N * 128 * 2);
    float*  a1s  = (float*)alloc((size_t)N * 8 * 4);
    float*  a1d  = (float*)alloc((size_t)N * 8 * 4);
    float*  a2s  = (float*)alloc((size_t)N * 4);
    float*  a2d  = (float*)alloc((size_t)N * 4);
    __bf16* Wb1  = (__bf16*)alloc((size_t)512 * 64 * 2);
    int* deg    = (int*)alloc((size_t)2 * N * 4);  // deg | cursor
    int* cursor = deg + N;
    int* row_start = (int*)alloc((size_t)(N + 1) * 4);
    int* csr_src   = (int*)alloc((size_t)E2 * 4);
    int nbscan = (N + 2047) / 2048;
    int* partials  = (int*)alloc((size_t)nbscan * 4);
    (void)ws_size; (void)n_in; (void)out_size;

    hipMemsetAsync(deg, 0, (size_t)2 * N * 4, stream);
    int eb = (E2 + 255) / 256;
    k_hist<<<eb, 256, 0, stream>>>(ei, E, E2, deg);
    k_scanA<<<nbscan, 256, 0, stream>>>(deg, partials, N);
    k_scanB<<<1, 64, 0, stream>>>(partials, nbscan, row_start, N);
    k_scanC<<<nbscan, 256, 0, stream>>>(deg, partials, row_start, N);
    k_scatter<<<eb, 256, 0, stream>>>(ei, E, E2, row_start, cursor, csr_src);

    int gb64 = (N + 63) / 64;
    int nb4 = (N + 3) / 4;
    k_wconv<<<128, 256, 0, stream>>>(W1, Wb1);
    k_gemm1<<<gb64, 256, 0, stream>>>(x, Wb1, h1, h1b, N);
    k_att1<<<(N * 8 + 255) / 256, 256, 0, stream>>>(h1, as1, ad1, a1s, a1d, N * 8);
    k_gat1<<<nb4, 256, 0, stream>>>(row_start, csr_src, h1b, a1s, a1d, b1, hmid, N);
    k_gemm2<<<gb64, 256, 0, stream>>>(hmid, W2, h2, h2b, N);
    k_att2<<<nb4, 256, 0, stream>>>(h2, as2, ad2, a2s, a2d, N);
    k_gat2<<<nb4, 256, 0, stream>>>(row_start, csr_src, h2b, a2s, a2d, b2, (float*)d_out, N);
}

// Round 21
// 208.776 us; speedup vs baseline: 3.1030x; 1.0798x over previous
//
#include <hip/hip_runtime.h>
#include <cstdint>

typedef __attribute__((ext_vector_type(8))) __bf16 bf16x8;
typedef __attribute__((ext_vector_type(4))) float f32x4;

// ---------------- CSR build ----------------

__global__ __launch_bounds__(256) void k_hist(const int* __restrict__ ei,
        int E, int E2, int* __restrict__ deg) {
    int e = blockIdx.x * 256 + threadIdx.x;
    if (e >= E2) return;
    int dst = (e < E) ? ei[E + e] : (e - E);
    atomicAdd(&deg[dst], 1);
}

// per-2048-chunk sums
__global__ __launch_bounds__(256) void k_scanA(const int* __restrict__ deg,
        int* __restrict__ partials, int N) {
    int t = threadIdx.x;
    int base = blockIdx.x * 2048 + t * 8;
    int s = 0;
    #pragma unroll
    for (int j = 0; j < 8; ++j) { int i = base + j; if (i < N) s += deg[i]; }
    #pragma unroll
    for (int off = 32; off >= 1; off >>= 1) s += __shfl_xor(s, off, 64);
    __shared__ int ws[4];
    if ((t & 63) == 0) ws[t >> 6] = s;
    __syncthreads();
    if (t == 0) partials[blockIdx.x] = ws[0] + ws[1] + ws[2] + ws[3];
}

// block-local scan + inline prefix over raw partials (nb small)
__global__ __launch_bounds__(256) void k_scanC(const int* __restrict__ deg,
        const int* __restrict__ partials, int* __restrict__ row_start,
        int N, int nb) {
    int t = threadIdx.x;
    int bid = blockIdx.x;
    int boff = 0;
    for (int b = 0; b < bid; ++b) boff += partials[b];
    int base = bid * 2048 + t * 8;
    int v[8], s = 0;
    #pragma unroll
    for (int j = 0; j < 8; ++j) { int i = base + j; v[j] = (i < N) ? deg[i] : 0; s += v[j]; }
    int lane = t & 63, w = t >> 6;
    int incl = s;
    #pragma unroll
    for (int d = 1; d < 64; d <<= 1) {
        int u = __shfl_up(incl, d, 64);
        if (lane >= d) incl += u;
    }
    __shared__ int wsum[4];
    if (lane == 63) wsum[w] = incl;
    __syncthreads();
    int woff = 0;
    #pragma unroll
    for (int i = 0; i < 4; ++i) if (i < w) woff += wsum[i];
    int run = boff + woff + incl - s;
    #pragma unroll
    for (int j = 0; j < 8; ++j) {
        int i = base + j;
        if (i < N) row_start[i] = run;
        run += v[j];
    }
    if (bid == 0 && t == 0) {
        int tot = 0;
        for (int b = 0; b < nb; ++b) tot += partials[b];
        row_start[N] = tot;
    }
}

__global__ __launch_bounds__(256) void k_scatter(const int* __restrict__ ei,
        int E, int E2, const int* __restrict__ row_start, int* __restrict__ cursor,
        int* __restrict__ csr_src) {
    int e = blockIdx.x * 256 + threadIdx.x;
    if (e >= E2) return;
    int src, dst;
    if (e < E) { src = ei[e]; dst = ei[E + e]; }
    else       { src = e - E; dst = src; }
    int pos = row_start[dst] + atomicAdd(&cursor[dst], 1);
    csr_src[pos] = src;
}

// ---------------- W1/W2 -> fragment-linear bf16 (once) ----------------
// W1 (512x64): Wb1[((s*4+ct)*64+lane)*8+j], k=s*32+g*8+j, n=ct*16+(lane&15), g=lane>>4
// W2 (64x128): Wb2[((s*8+ct)*64+lane)*8+j], same k decomp (s in {0,1}), n=ct*16+(lane&15)

__global__ __launch_bounds__(256) void k_wconv(const float* __restrict__ W1,
        const float* __restrict__ W2, __bf16* __restrict__ Wb1,
        __bf16* __restrict__ Wb2) {
    int e = blockIdx.x * 256 + threadIdx.x;   // 32768 + 8192
    if (e < 32768) {
        int k = e >> 6, n = e & 63;
        int s = k >> 5, g = (k >> 3) & 3, j = k & 7;
        int ct = n >> 4;
        int lane = (n & 15) | (g << 4);
        Wb1[(((s * 4 + ct) * 64 + lane) << 3) + j] = (__bf16)W1[e];
    } else {
        int e2 = e - 32768;                   // 64x128
        int k = e2 >> 7, n = e2 & 127;
        int s = k >> 5, g = (k >> 3) & 3, j = k & 7;
        int ct = n >> 4;
        int lane = (n & 15) | (g << 4);
        Wb2[(((s * 8 + ct) * 64 + lane) << 3) + j] = (__bf16)W2[e2];
    }
}

// ---------------- GEMM1 (bf16 MFMA, K-split x2): partials h1p ----------------
// grid = 2 * ceil(N/64); half = bid&1 covers K range [half*256, half*256+256).
// Block = 4 waves = 64 rows. B-frags from 64KB L2-resident Wb1.

__global__ __launch_bounds__(256) void k_gemm1(const float* __restrict__ x,
        const __bf16* __restrict__ Wb, float* __restrict__ h1p, int N) {
    int bid = blockIdx.x;
    int half = bid & 1, tile = bid >> 1;
    int t = threadIdx.x;
    int l = t & 63, w = t >> 6;
    int g = l >> 4;
    int arow = tile * 64 + w * 16 + (l & 15);
    const float* xbase = x + (size_t)min(arow, N - 1) * 512 + g * 8;

    f32x4 acc[4] = {{0.f,0.f,0.f,0.f},{0.f,0.f,0.f,0.f},
                    {0.f,0.f,0.f,0.f},{0.f,0.f,0.f,0.f}};
    int s0 = half * 8;
    #pragma unroll 4
    for (int si = 0; si < 8; ++si) {
        int s = s0 + si;
        float4 xa = *(const float4*)(xbase + s * 32);
        float4 xb = *(const float4*)(xbase + s * 32 + 4);
        bf16x8 a;
        a[0] = (__bf16)xa.x; a[1] = (__bf16)xa.y; a[2] = (__bf16)xa.z; a[3] = (__bf16)xa.w;
        a[4] = (__bf16)xb.x; a[5] = (__bf16)xb.y; a[6] = (__bf16)xb.z; a[7] = (__bf16)xb.w;
        #pragma unroll
        for (int ct = 0; ct < 4; ++ct) {
            bf16x8 b = *reinterpret_cast<const bf16x8*>(Wb + (((s * 4 + ct) * 64 + l) << 3));
            acc[ct] = __builtin_amdgcn_mfma_f32_16x16x32_bf16(a, b, acc[ct], 0, 0, 0);
        }
    }
    float* hp = h1p + (size_t)half * N * 64;
    int orow0 = tile * 64 + w * 16 + g * 4;
    #pragma unroll
    for (int ct = 0; ct < 4; ++ct) {
        int col = ct * 16 + (l & 15);
        #pragma unroll
        for (int r = 0; r < 4; ++r) {
            int row = orow0 + r;
            if (row < N) hp[(size_t)row * 64 + col] = acc[ct][r];
        }
    }
}

// ---------------- combine halves + attention coeffs + h1b (bf16) ----------

__global__ __launch_bounds__(256) void k_att1(const float* __restrict__ h1p,
        const float* __restrict__ att_src, const float* __restrict__ att_dst,
        float* __restrict__ a_s, float* __restrict__ a_d,
        __bf16* __restrict__ h1b, int N) {
    int i = blockIdx.x * 256 + threadIdx.x;
    int NH = N * 8;
    if (i >= NH) return;
    int h = i & 7;
    const float* p0 = h1p + (size_t)i * 8;
    const float* p1 = h1p + (size_t)N * 64 + (size_t)i * 8;
    float4 a0 = *(const float4*)p0,       a1 = *(const float4*)(p0 + 4);
    float4 b0 = *(const float4*)p1,       b1 = *(const float4*)(p1 + 4);
    float v[8] = { a0.x + b0.x, a0.y + b0.y, a0.z + b0.z, a0.w + b0.w,
                   a1.x + b1.x, a1.y + b1.y, a1.z + b1.z, a1.w + b1.w };
    const float* sp = att_src + h * 8;
    const float* dp = att_dst + h * 8;
    float s = 0.f, d = 0.f;
    bf16x8 hb;
    #pragma unroll
    for (int c = 0; c < 8; ++c) {
        s += v[c] * sp[c];
        d += v[c] * dp[c];
        hb[c] = (__bf16)v[c];
    }
    a_s[i] = s; a_d[i] = d;
    *(bf16x8*)(h1b + (size_t)i * 8) = hb;
}

// ---------------- GAT layer 1 (H=8, C=8) -> bf16 hmid_b (bias + ELU) --------

__global__ __launch_bounds__(256) void k_gat1(
        const int* __restrict__ row_start, const int* __restrict__ csr_src,
        const __bf16* __restrict__ h1b,
        const float* __restrict__ a_src, const float* __restrict__ a_dst,
        const float* __restrict__ bias, __bf16* __restrict__ outp, int N) {
    int node = blockIdx.x * 4 + (threadIdx.x >> 6);
    int lane = threadIdx.x & 63;
    if (node >= N) return;
    int j = lane >> 3, c = lane & 7;
    int start = row_start[node], end = row_start[node + 1];
    float adc = a_dst[(size_t)node * 8 + c];

    float acc[8] = {};
    float wsum = 0.f;
    #pragma unroll 2
    for (int base = start; base < end; base += 8) {
        int idx = base + j;
        if (idx < end) {
            int s = csr_src[idx];
            float a = a_src[(size_t)s * 8 + c] + adc;
            a = a > 0.f ? a : 0.2f * a;
            float w = __expf(a);
            wsum += w;
            bf16x8 v = *(const bf16x8*)(h1b + (size_t)s * 64 + c * 8);
            #pragma unroll
            for (int e = 0; e < 8; ++e) acc[e] = fmaf(w, (float)v[e], acc[e]);
        }
    }
    #pragma unroll
    for (int off = 8; off <= 32; off <<= 1) {
        wsum += __shfl_xor(wsum, off, 64);
        #pragma unroll
        for (int e = 0; e < 8; ++e) acc[e] += __shfl_xor(acc[e], off, 64);
    }
    if (j == 0) {
        float inv = 1.f / (wsum + 1e-16f);
        const float* bp = bias + c * 8;
        bf16x8 ob;
        #pragma unroll
        for (int e = 0; e < 8; ++e) {
            float v = acc[e] * inv + bp[e];
            v = v > 0.f ? v : __expf(v) - 1.f;  // ELU
            ob[e] = (__bf16)v;
        }
        *(bf16x8*)(outp + (size_t)node * 64 + c * 8) = ob;
    }
}

// ---------------- GEMM2 (bf16 MFMA) + fused att2: hmid_b @ Wb2 -> h2b, a2 ---
// Block = 4 waves = 64 rows x 128 cols. A-frags are direct 16B loads from
// bf16 hmid_b; B-frags from 16KB L2-resident Wb2. Epilogue computes
// a2s/a2d = h2 . att vectors via 16-lane shfl reduction (h2 fp32 never hits
// memory), and writes bf16 h2b for the gather.

__global__ __launch_bounds__(256) void k_gemm2(const __bf16* __restrict__ hb,
        const __bf16* __restrict__ Wb, const float* __restrict__ att_src,
        const float* __restrict__ att_dst, __bf16* __restrict__ h2b,
        float* __restrict__ a2s, float* __restrict__ a2d, int N) {
    int t = threadIdx.x;
    int l = t & 63, w = t >> 6;
    int g = l >> 4;
    int arow = blockIdx.x * 64 + w * 16 + (l & 15);
    const __bf16* abase = hb + (size_t)min(arow, N - 1) * 64 + g * 8;

    bf16x8 a0 = *(const bf16x8*)(abase);
    bf16x8 a1 = *(const bf16x8*)(abase + 32);
    f32x4 acc[8];
    #pragma unroll
    for (int ct = 0; ct < 8; ++ct) acc[ct] = (f32x4){0.f,0.f,0.f,0.f};
    #pragma unroll
    for (int ct = 0; ct < 8; ++ct) {
        bf16x8 b0 = *reinterpret_cast<const bf16x8*>(Wb + ((ct * 64 + l) << 3));
        bf16x8 b1 = *reinterpret_cast<const bf16x8*>(Wb + (((8 + ct) * 64 + l) << 3));
        acc[ct] = __builtin_amdgcn_mfma_f32_16x16x32_bf16(a0, b0, acc[ct], 0, 0, 0);
        acc[ct] = __builtin_amdgcn_mfma_f32_16x16x32_bf16(a1, b1, acc[ct], 0, 0, 0);
    }
    int orow0 = blockIdx.x * 64 + w * 16 + g * 4;
    float sp[4] = {0.f,0.f,0.f,0.f}, dp[4] = {0.f,0.f,0.f,0.f};
    #pragma unroll
    for (int ct = 0; ct < 8; ++ct) {
        int col = ct * 16 + (l & 15);
        float as = att_src[col], ad = att_dst[col];
        #pragma unroll
        for (int r = 0; r < 4; ++r) {
            int row = orow0 + r;
            float v = acc[ct][r];
            if (row < N) h2b[(size_t)row * 128 + col] = (__bf16)v;
            sp[r] = fmaf(v, as, sp[r]);
            dp[r] = fmaf(v, ad, dp[r]);
        }
    }
    // reduce over the 16 lanes sharing (w,g) => full 128-col dot
    #pragma unroll
    for (int off = 1; off <= 8; off <<= 1) {
        #pragma unroll
        for (int r = 0; r < 4; ++r) {
            sp[r] += __shfl_xor(sp[r], off, 64);
            dp[r] += __shfl_xor(dp[r], off, 64);
        }
    }
    if ((l & 15) == 0) {
        #pragma unroll
        for (int r = 0; r < 4; ++r) {
            int row = orow0 + r;
            if (row < N) { a2s[row] = sp[r]; a2d[row] = dp[r]; }
        }
    }
}

// ---------------- GAT layer 2 (H=1, C=128), multi-edge lanes + bias ----------

__global__ __launch_bounds__(256) void k_gat2(
        const int* __restrict__ row_start, const int* __restrict__ csr_src,
        const __bf16* __restrict__ h2b,
        const float* __restrict__ a_src, const float* __restrict__ a_dst,
        const float* __restrict__ bias, float* __restrict__ outp, int N) {
    int node = blockIdx.x * 4 + (threadIdx.x >> 6);
    int lane = threadIdx.x & 63;
    if (node >= N) return;
    int j = lane >> 4, c = lane & 15;
    int start = row_start[node], end = row_start[node + 1];
    float adst = a_dst[node];

    float acc[8] = {};
    float wsum = 0.f;
    #pragma unroll 2
    for (int base = start; base < end; base += 4) {
        int idx = base + j;
        if (idx < end) {
            int s = csr_src[idx];
            float a = a_src[s] + adst;
            a = a > 0.f ? a : 0.2f * a;
            float w = __expf(a);
            wsum += w;
            bf16x8 v = *(const bf16x8*)(h2b + (size_t)s * 128 + c * 8);
            #pragma unroll
            for (int e = 0; e < 8; ++e) acc[e] = fmaf(w, (float)v[e], acc[e]);
        }
    }
    #pragma unroll
    for (int off = 16; off <= 32; off <<= 1) {
        wsum += __shfl_xor(wsum, off, 64);
        #pragma unroll
        for (int e = 0; e < 8; ++e) acc[e] += __shfl_xor(acc[e], off, 64);
    }
    if (j == 0) {
        float inv = 1.f / (wsum + 1e-16f);
        float* op = outp + (size_t)node * 128 + c * 8;
        const float* bp = bias + c * 8;
        #pragma unroll
        for (int e = 0; e < 8; ++e)
            op[e] = acc[e] * inv + bp[e];
    }
}

// ---------------- launcher ----------------

extern "C" void kernel_launch(void* const* d_in, const int* in_sizes, int n_in,
                              void* d_out, int out_size, void* d_ws, size_t ws_size,
                              hipStream_t stream) {
    const float* x   = (const float*)d_in[0];
    const int*   ei  = (const int*)d_in[1];     // integer inputs arrive as int32
    const float* W1  = (const float*)d_in[2];
    const float* as1 = (const float*)d_in[3];
    const float* ad1 = (const float*)d_in[4];
    const float* b1  = (const float*)d_in[5];
    const float* W2  = (const float*)d_in[6];
    const float* as2 = (const float*)d_in[7];
    const float* ad2 = (const float*)d_in[8];
    const float* b2  = (const float*)d_in[9];
    int N  = in_sizes[0] / 512;
    int E  = in_sizes[1] / 2;
    int E2 = E + N;

    char* wsp = (char*)d_ws;
    size_t off = 0;
    auto alloc = [&](size_t bytes) {
        char* p = wsp + off;
        off = (off + bytes + 255) & ~(size_t)255;
        return p;
    };
    float*  h1p   = (float*)alloc((size_t)2 * N * 64 * 4);   // K-split partials
    __bf16* h1b   = (__bf16*)alloc((size_t)N * 64 * 2);
    __bf16* hmidb = (__bf16*)alloc((size_t)N * 64 * 2);
    __bf16* h2b   = (__bf16*)alloc((size_t)N * 128 * 2);
    float*  a1s   = (float*)alloc((size_t)N * 8 * 4);
    float*  a1d   = (float*)alloc((size_t)N * 8 * 4);
    float*  a2s   = (float*)alloc((size_t)N * 4);
    float*  a2d   = (float*)alloc((size_t)N * 4);
    __bf16* Wb1   = (__bf16*)alloc((size_t)512 * 64 * 2);
    __bf16* Wb2   = (__bf16*)alloc((size_t)64 * 128 * 2);
    int* deg    = (int*)alloc((size_t)2 * N * 4);  // deg | cursor
    int* cursor = deg + N;
    int* row_start = (int*)alloc((size_t)(N + 1) * 4);
    int* csr_src   = (int*)alloc((size_t)E2 * 4);
    int nbscan = (N + 2047) / 2048;
    int* partials  = (int*)alloc((size_t)nbscan * 4);
    (void)ws_size; (void)n_in; (void)out_size;

    hipMemsetAsync(deg, 0, (size_t)2 * N * 4, stream);
    int eb = (E2 + 255) / 256;
    k_hist<<<eb, 256, 0, stream>>>(ei, E, E2, deg);
    k_scanA<<<nbscan, 256, 0, stream>>>(deg, partials, N);
    k_scanC<<<nbscan, 256, 0, stream>>>(deg, partials, row_start, N, nbscan);
    k_scatter<<<eb, 256, 0, stream>>>(ei, E, E2, row_start, cursor, csr_src);

    int gb64 = (N + 63) / 64;
    int nb4 = (N + 3) / 4;
    k_wconv<<<160, 256, 0, stream>>>(W1, W2, Wb1, Wb2);
    k_gemm1<<<gb64 * 2, 256, 0, stream>>>(x, Wb1, h1p, N);
    k_att1<<<(N * 8 + 255) / 256, 256, 0, stream>>>(h1p, as1, ad1, a1s, a1d, h1b, N);
    k_gat1<<<nb4, 256, 0, stream>>>(row_start, csr_src, h1b, a1s, a1d, b1, hmidb, N);
    k_gemm2<<<gb64, 256, 0, stream>>>(hmidb, Wb2, as2, ad2, h2b, a2s, a2d, N);
    k_gat2<<<nb4, 256, 0, stream>>>(row_start, csr_src, h2b, a2s, a2d, b2, (float*)d_out, N);
}

// Round 23
// 208.141 us; speedup vs baseline: 3.1125x; 1.0031x over previous
//
#include <hip/hip_runtime.h>
#include <cstdint>

typedef __attribute__((ext_vector_type(8))) __bf16 bf16x8;
typedef __attribute__((ext_vector_type(4))) float f32x4;

// ---------------- CSR build ----------------

__global__ __launch_bounds__(256) void k_hist(const int* __restrict__ ei,
        int E, int E2, int* __restrict__ deg) {
    int e = blockIdx.x * 256 + threadIdx.x;
    if (e >= E2) return;
    int dst = (e < E) ? ei[E + e] : (e - E);
    atomicAdd(&deg[dst], 1);
}

// per-2048-chunk sums
__global__ __launch_bounds__(256) void k_scanA(const int* __restrict__ deg,
        int* __restrict__ partials, int N) {
    int t = threadIdx.x;
    int base = blockIdx.x * 2048 + t * 8;
    int s = 0;
    #pragma unroll
    for (int j = 0; j < 8; ++j) { int i = base + j; if (i < N) s += deg[i]; }
    #pragma unroll
    for (int off = 32; off >= 1; off >>= 1) s += __shfl_xor(s, off, 64);
    __shared__ int ws[4];
    if ((t & 63) == 0) ws[t >> 6] = s;
    __syncthreads();
    if (t == 0) partials[blockIdx.x] = ws[0] + ws[1] + ws[2] + ws[3];
}

// block-local scan + inline prefix over raw partials (nb small)
__global__ __launch_bounds__(256) void k_scanC(const int* __restrict__ deg,
        const int* __restrict__ partials, int* __restrict__ row_start,
        int N, int nb) {
    int t = threadIdx.x;
    int bid = blockIdx.x;
    int boff = 0;
    for (int b = 0; b < bid; ++b) boff += partials[b];
    int base = bid * 2048 + t * 8;
    int v[8], s = 0;
    #pragma unroll
    for (int j = 0; j < 8; ++j) { int i = base + j; v[j] = (i < N) ? deg[i] : 0; s += v[j]; }
    int lane = t & 63, w = t >> 6;
    int incl = s;
    #pragma unroll
    for (int d = 1; d < 64; d <<= 1) {
        int u = __shfl_up(incl, d, 64);
        if (lane >= d) incl += u;
    }
    __shared__ int wsum[4];
    if (lane == 63) wsum[w] = incl;
    __syncthreads();
    int woff = 0;
    #pragma unroll
    for (int i = 0; i < 4; ++i) if (i < w) woff += wsum[i];
    int run = boff + woff + incl - s;
    #pragma unroll
    for (int j = 0; j < 8; ++j) {
        int i = base + j;
        if (i < N) row_start[i] = run;
        run += v[j];
    }
    if (bid == 0 && t == 0) {
        int tot = 0;
        for (int b = 0; b < nb; ++b) tot += partials[b];
        row_start[N] = tot;
    }
}

__global__ __launch_bounds__(256) void k_scatter(const int* __restrict__ ei,
        int E, int E2, const int* __restrict__ row_start, int* __restrict__ cursor,
        int* __restrict__ csr_src) {
    int e = blockIdx.x * 256 + threadIdx.x;
    if (e >= E2) return;
    int src, dst;
    if (e < E) { src = ei[e]; dst = ei[E + e]; }
    else       { src = e - E; dst = src; }
    int pos = row_start[dst] + atomicAdd(&cursor[dst], 1);
    csr_src[pos] = src;
}

// ---------------- W1/W2 -> fragment-linear bf16 (once) ----------------
// W1 (512x64): Wb1[((s*4+ct)*64+lane)*8+j], k=s*32+g*8+j, n=ct*16+(lane&15), g=lane>>4
// W2 (64x128): Wb2[((s*8+ct)*64+lane)*8+j], same k decomp (s in {0,1}), n=ct*16+(lane&15)

__global__ __launch_bounds__(256) void k_wconv(const float* __restrict__ W1,
        const float* __restrict__ W2, __bf16* __restrict__ Wb1,
        __bf16* __restrict__ Wb2) {
    int e = blockIdx.x * 256 + threadIdx.x;   // 32768 + 8192
    if (e < 32768) {
        int k = e >> 6, n = e & 63;
        int s = k >> 5, g = (k >> 3) & 3, j = k & 7;
        int ct = n >> 4;
        int lane = (n & 15) | (g << 4);
        Wb1[(((s * 4 + ct) * 64 + lane) << 3) + j] = (__bf16)W1[e];
    } else {
        int e2 = e - 32768;                   // 64x128
        int k = e2 >> 7, n = e2 & 127;
        int s = k >> 5, g = (k >> 3) & 3, j = k & 7;
        int ct = n >> 4;
        int lane = (n & 15) | (g << 4);
        Wb2[(((s * 8 + ct) * 64 + lane) << 3) + j] = (__bf16)W2[e2];
    }
}

// ---------------- GEMM1 (bf16 MFMA, K-split x2): partials h1p ----------------
// grid = 2 * ceil(N/64); half = bid&1 covers K range [half*256, half*256+256).
// Block = 4 waves = 64 rows. B-frags from 64KB L2-resident Wb1.

__global__ __launch_bounds__(256) void k_gemm1(const float* __restrict__ x,
        const __bf16* __restrict__ Wb, float* __restrict__ h1p, int N) {
    int bid = blockIdx.x;
    int half = bid & 1, tile = bid >> 1;
    int t = threadIdx.x;
    int l = t & 63, w = t >> 6;
    int g = l >> 4;
    int arow = tile * 64 + w * 16 + (l & 15);
    const float* xbase = x + (size_t)min(arow, N - 1) * 512 + g * 8;

    f32x4 acc[4] = {{0.f,0.f,0.f,0.f},{0.f,0.f,0.f,0.f},
                    {0.f,0.f,0.f,0.f},{0.f,0.f,0.f,0.f}};
    int s0 = half * 8;
    #pragma unroll 4
    for (int si = 0; si < 8; ++si) {
        int s = s0 + si;
        float4 xa = *(const float4*)(xbase + s * 32);
        float4 xb = *(const float4*)(xbase + s * 32 + 4);
        bf16x8 a;
        a[0] = (__bf16)xa.x; a[1] = (__bf16)xa.y; a[2] = (__bf16)xa.z; a[3] = (__bf16)xa.w;
        a[4] = (__bf16)xb.x; a[5] = (__bf16)xb.y; a[6] = (__bf16)xb.z; a[7] = (__bf16)xb.w;
        #pragma unroll
        for (int ct = 0; ct < 4; ++ct) {
            bf16x8 b = *reinterpret_cast<const bf16x8*>(Wb + (((s * 4 + ct) * 64 + l) << 3));
            acc[ct] = __builtin_amdgcn_mfma_f32_16x16x32_bf16(a, b, acc[ct], 0, 0, 0);
        }
    }
    float* hp = h1p + (size_t)half * N * 64;
    int orow0 = tile * 64 + w * 16 + g * 4;
    #pragma unroll
    for (int ct = 0; ct < 4; ++ct) {
        int col = ct * 16 + (l & 15);
        #pragma unroll
        for (int r = 0; r < 4; ++r) {
            int row = orow0 + r;
            if (row < N) hp[(size_t)row * 64 + col] = acc[ct][r];
        }
    }
}

// ---------------- combine halves + attention coeffs + h1b (bf16) ----------

__global__ __launch_bounds__(256) void k_att1(const float* __restrict__ h1p,
        const float* __restrict__ att_src, const float* __restrict__ att_dst,
        float* __restrict__ a_s, float* __restrict__ a_d,
        __bf16* __restrict__ h1b, int N) {
    int i = blockIdx.x * 256 + threadIdx.x;
    int NH = N * 8;
    if (i >= NH) return;
    int h = i & 7;
    const float* p0 = h1p + (size_t)i * 8;
    const float* p1 = h1p + (size_t)N * 64 + (size_t)i * 8;
    float4 a0 = *(const float4*)p0,       a1 = *(const float4*)(p0 + 4);
    float4 b0 = *(const float4*)p1,       b1 = *(const float4*)(p1 + 4);
    float v[8] = { a0.x + b0.x, a0.y + b0.y, a0.z + b0.z, a0.w + b0.w,
                   a1.x + b1.x, a1.y + b1.y, a1.z + b1.z, a1.w + b1.w };
    const float* sp = att_src + h * 8;
    const float* dp = att_dst + h * 8;
    float s = 0.f, d = 0.f;
    bf16x8 hb;
    #pragma unroll
    for (int c = 0; c < 8; ++c) {
        s += v[c] * sp[c];
        d += v[c] * dp[c];
        hb[c] = (__bf16)v[c];
    }
    a_s[i] = s; a_d[i] = d;
    *(bf16x8*)(h1b + (size_t)i * 8) = hb;
}

// ---------------- GAT layer 1 (H=8, C=8) -> bf16 hmid_b (bias + ELU) --------

__global__ __launch_bounds__(256) void k_gat1(
        const int* __restrict__ row_start, const int* __restrict__ csr_src,
        const __bf16* __restrict__ h1b,
        const float* __restrict__ a_src, const float* __restrict__ a_dst,
        const float* __restrict__ bias, __bf16* __restrict__ outp, int N) {
    int node = blockIdx.x * 4 + (threadIdx.x >> 6);
    int lane = threadIdx.x & 63;
    if (node >= N) return;
    int j = lane >> 3, c = lane & 7;
    int start = row_start[node], end = row_start[node + 1];
    float adc = a_dst[(size_t)node * 8 + c];

    float acc[8] = {};
    float wsum = 0.f;
    #pragma unroll 2
    for (int base = start; base < end; base += 8) {
        int idx = base + j;
        if (idx < end) {
            int s = csr_src[idx];
            float a = a_src[(size_t)s * 8 + c] + adc;
            a = a > 0.f ? a : 0.2f * a;
            float w = __expf(a);
            wsum += w;
            bf16x8 v = *(const bf16x8*)(h1b + (size_t)s * 64 + c * 8);
            #pragma unroll
            for (int e = 0; e < 8; ++e) acc[e] = fmaf(w, (float)v[e], acc[e]);
        }
    }
    #pragma unroll
    for (int off = 8; off <= 32; off <<= 1) {
        wsum += __shfl_xor(wsum, off, 64);
        #pragma unroll
        for (int e = 0; e < 8; ++e) acc[e] += __shfl_xor(acc[e], off, 64);
    }
    if (j == 0) {
        float inv = 1.f / (wsum + 1e-16f);
        const float* bp = bias + c * 8;
        bf16x8 ob;
        #pragma unroll
        for (int e = 0; e < 8; ++e) {
            float v = acc[e] * inv + bp[e];
            v = v > 0.f ? v : __expf(v) - 1.f;  // ELU
            ob[e] = (__bf16)v;
        }
        *(bf16x8*)(outp + (size_t)node * 64 + c * 8) = ob;
    }
}

// ---------------- GEMM2 (bf16 MFMA) + fused att2: hmid_b @ Wb2 -> h2b, a2 ---
// Block = 4 waves = 64 rows x 128 cols. A-frags are direct 16B loads from
// bf16 hmid_b; B-frags from 16KB L2-resident Wb2. Epilogue computes
// a2s/a2d = h2 . att vectors via 16-lane shfl reduction (h2 fp32 never hits
// memory), and writes bf16 h2b for the gather.

__global__ __launch_bounds__(256) void k_gemm2(const __bf16* __restrict__ hb,
        const __bf16* __restrict__ Wb, const float* __restrict__ att_src,
        const float* __restrict__ att_dst, __bf16* __restrict__ h2b,
        float* __restrict__ a2s, float* __restrict__ a2d, int N) {
    int t = threadIdx.x;
    int l = t & 63, w = t >> 6;
    int g = l >> 4;
    int arow = blockIdx.x * 64 + w * 16 + (l & 15);
    const __bf16* abase = hb + (size_t)min(arow, N - 1) * 64 + g * 8;

    bf16x8 a0 = *(const bf16x8*)(abase);
    bf16x8 a1 = *(const bf16x8*)(abase + 32);
    f32x4 acc[8];
    #pragma unroll
    for (int ct = 0; ct < 8; ++ct) acc[ct] = (f32x4){0.f,0.f,0.f,0.f};
    #pragma unroll
    for (int ct = 0; ct < 8; ++ct) {
        bf16x8 b0 = *reinterpret_cast<const bf16x8*>(Wb + ((ct * 64 + l) << 3));
        bf16x8 b1 = *reinterpret_cast<const bf16x8*>(Wb + (((8 + ct) * 64 + l) << 3));
        acc[ct] = __builtin_amdgcn_mfma_f32_16x16x32_bf16(a0, b0, acc[ct], 0, 0, 0);
        acc[ct] = __builtin_amdgcn_mfma_f32_16x16x32_bf16(a1, b1, acc[ct], 0, 0, 0);
    }
    int orow0 = blockIdx.x * 64 + w * 16 + g * 4;
    float sp[4] = {0.f,0.f,0.f,0.f}, dp[4] = {0.f,0.f,0.f,0.f};
    #pragma unroll
    for (int ct = 0; ct < 8; ++ct) {
        int col = ct * 16 + (l & 15);
        float as = att_src[col], ad = att_dst[col];
        #pragma unroll
        for (int r = 0; r < 4; ++r) {
            int row = orow0 + r;
            float v = acc[ct][r];
            if (row < N) h2b[(size_t)row * 128 + col] = (__bf16)v;
            sp[r] = fmaf(v, as, sp[r]);
            dp[r] = fmaf(v, ad, dp[r]);
        }
    }
    // reduce over the 16 lanes sharing (w,g) => full 128-col dot
    #pragma unroll
    for (int off = 1; off <= 8; off <<= 1) {
        #pragma unroll
        for (int r = 0; r < 4; ++r) {
            sp[r] += __shfl_xor(sp[r], off, 64);
            dp[r] += __shfl_xor(dp[r], off, 64);
        }
    }
    if ((l & 15) == 0) {
        #pragma unroll
        for (int r = 0; r < 4; ++r) {
            int row = orow0 + r;
            if (row < N) { a2s[row] = sp[r]; a2d[row] = dp[r]; }
        }
    }
}

// ---------------- GAT layer 2 (H=1, C=128), multi-edge lanes + bias ----------

__global__ __launch_bounds__(256) void k_gat2(
        const int* __restrict__ row_start, const int* __restrict__ csr_src,
        const __bf16* __restrict__ h2b,
        const float* __restrict__ a_src, const float* __restrict__ a_dst,
        const float* __restrict__ bias, float* __restrict__ outp, int N) {
    int node = blockIdx.x * 4 + (threadIdx.x >> 6);
    int lane = threadIdx.x & 63;
    if (node >= N) return;
    int j = lane >> 4, c = lane & 15;
    int start = row_start[node], end = row_start[node + 1];
    float adst = a_dst[node];

    float acc[8] = {};
    float wsum = 0.f;
    #pragma unroll 2
    for (int base = start; base < end; base += 4) {
        int idx = base + j;
        if (idx < end) {
            int s = csr_src[idx];
            float a = a_src[s] + adst;
            a = a > 0.f ? a : 0.2f * a;
            float w = __expf(a);
            wsum += w;
            bf16x8 v = *(const bf16x8*)(h2b + (size_t)s * 128 + c * 8);
            #pragma unroll
            for (int e = 0; e < 8; ++e) acc[e] = fmaf(w, (float)v[e], acc[e]);
        }
    }
    #pragma unroll
    for (int off = 16; off <= 32; off <<= 1) {
        wsum += __shfl_xor(wsum, off, 64);
        #pragma unroll
        for (int e = 0; e < 8; ++e) acc[e] += __shfl_xor(acc[e], off, 64);
    }
    if (j == 0) {
        float inv = 1.f / (wsum + 1e-16f);
        float* op = outp + (size_t)node * 128 + c * 8;
        const float* bp = bias + c * 8;
        #pragma unroll
        for (int e = 0; e < 8; ++e)
            op[e] = acc[e] * inv + bp[e];
    }
}

// ---------------- launcher ----------------

extern "C" void kernel_launch(void* const* d_in, const int* in_sizes, int n_in,
                              void* d_out, int out_size, void* d_ws, size_t ws_size,
                              hipStream_t stream) {
    const float* x   = (const float*)d_in[0];
    const int*   ei  = (const int*)d_in[1];     // integer inputs arrive as int32
    const float* W1  = (const float*)d_in[2];
    const float* as1 = (const float*)d_in[3];
    const float* ad1 = (const float*)d_in[4];
    const float* b1  = (const float*)d_in[5];
    const float* W2  = (const float*)d_in[6];
    const float* as2 = (const float*)d_in[7];
    const float* ad2 = (const float*)d_in[8];
    const float* b2  = (const float*)d_in[9];
    int N  = in_sizes[0] / 512;
    int E  = in_sizes[1] / 2;
    int E2 = E + N;

    char* wsp = (char*)d_ws;
    size_t off = 0;
    auto alloc = [&](size_t bytes) {
        char* p = wsp + off;
        off = (off + bytes + 255) & ~(size_t)255;
        return p;
    };
    float*  h1p   = (float*)alloc((size_t)2 * N * 64 * 4);   // K-split partials
    __bf16* h1b   = (__bf16*)alloc((size_t)N * 64 * 2);
    __bf16* hmidb = (__bf16*)alloc((size_t)N * 64 * 2);
    __bf16* h2b   = (__bf16*)alloc((size_t)N * 128 * 2);
    float*  a1s   = (float*)alloc((size_t)N * 8 * 4);
    float*  a1d   = (float*)alloc((size_t)N * 8 * 4);
    float*  a2s   = (float*)alloc((size_t)N * 4);
    float*  a2d   = (float*)alloc((size_t)N * 4);
    __bf16* Wb1   = (__bf16*)alloc((size_t)512 * 64 * 2);
    __bf16* Wb2   = (__bf16*)alloc((size_t)64 * 128 * 2);
    int* deg    = (int*)alloc((size_t)2 * N * 4);  // deg | cursor
    int* cursor = deg + N;
    int* row_start = (int*)alloc((size_t)(N + 1) * 4);
    int* csr_src   = (int*)alloc((size_t)E2 * 4);
    int nbscan = (N + 2047) / 2048;
    int* partials  = (int*)alloc((size_t)nbscan * 4);
    (void)ws_size; (void)n_in; (void)out_size;

    hipMemsetAsync(deg, 0, (size_t)2 * N * 4, stream);
    int eb = (E2 + 255) / 256;
    k_hist<<<eb, 256, 0, stream>>>(ei, E, E2, deg);
    k_scanA<<<nbscan, 256, 0, stream>>>(deg, partials, N);
    k_scanC<<<nbscan, 256, 0, stream>>>(deg, partials, row_start, N, nbscan);
    k_scatter<<<eb, 256, 0, stream>>>(ei, E, E2, row_start, cursor, csr_src);

    int gb64 = (N + 63) / 64;
    int nb4 = (N + 3) / 4;
    k_wconv<<<160, 256, 0, stream>>>(W1, W2, Wb1, Wb2);
    k_gemm1<<<gb64 * 2, 256, 0, stream>>>(x, Wb1, h1p, N);
    k_att1<<<(N * 8 + 255) / 256, 256, 0, stream>>>(h1p, as1, ad1, a1s, a1d, h1b, N);
    k_gat1<<<nb4, 256, 0, stream>>>(row_start, csr_src, h1b, a1s, a1d, b1, hmidb, N);
    k_gemm2<<<gb64, 256, 0, stream>>>(hmidb, Wb2, as2, ad2, h2b, a2s, a2d, N);
    k_gat2<<<nb4, 256, 0, stream>>>(row_start, csr_src, h2b, a2s, a2d, b2, (float*)d_out, N);
}